// Round 20
// baseline (569.653 us; speedup 1.0000x reference)
//
#include <hip/hip_runtime.h>
#include <hip/hip_bf16.h>

// ---------------- constants ----------------
#define N_NODES 51200
#define N_EDGES 204800
#define N_HNNZ  102400
#define N_HEDGES 10240
#define NB 1024          // batch (graphs)
#define NPG 50           // nodes per graph (51200/1024)
#define FXD 84
#define FP_DIM 2513
#define FP2 128
#define HID 512

typedef __attribute__((ext_vector_type(4))) float f32x4;
typedef __attribute__((ext_vector_type(8))) __bf16 bf16x8;
typedef __attribute__((ext_vector_type(4))) short short4_t;

static __device__ __forceinline__ unsigned short f2bf(float f) {
    unsigned u = __builtin_bit_cast(unsigned, f);
    u += 0x7FFFu + ((u >> 16) & 1u);   // round-to-nearest-even
    return (unsigned short)(u >> 16);
}
static __device__ __forceinline__ float bf2f(unsigned short u) {
    unsigned x = ((unsigned)u) << 16;
    return __builtin_bit_cast(float, x);
}

// bijective XCD-aware remap (m204 formula)
static __device__ __forceinline__ int xcd_swizzle(int orig, int nwg) {
    int q = nwg >> 3, r = nwg & 7;
    int xcd = orig & 7, off = orig >> 3;
    return (xcd < r ? xcd * (q + 1) : r * (q + 1) + (xcd - r) * q) + off;
}

// load 4 f32 as bf16 short4 with K-guards
static __device__ __forceinline__ short4_t ld4bf_f32(const float* p, int gk, int kend, bool kvec) {
    short4_t sv;
    float v0 = 0.f, v1 = 0.f, v2 = 0.f, v3 = 0.f;
    if (kvec && gk + 4 <= kend) {
        float4 f = *(const float4*)p;
        v0 = f.x; v1 = f.y; v2 = f.z; v3 = f.w;
    } else {
        v0 = p[0];
        if (gk + 1 < kend) v1 = p[1];
        if (gk + 2 < kend) v2 = p[2];
        if (gk + 3 < kend) v3 = p[3];
    }
    sv[0] = (short)f2bf(v0); sv[1] = (short)f2bf(v1);
    sv[2] = (short)f2bf(v2); sv[3] = (short)f2bf(v3);
    return sv;
}

// ---------------- CSR build ----------------
__global__ void histo_i(const int* __restrict__ keys, int* __restrict__ cnt, int n) {
    int i = blockIdx.x * 256 + threadIdx.x;
    if (i < n) atomicAdd(&cnt[keys[i]], 1);
}

// 3-phase parallel exclusive scan over 3 concatenated count arrays.
__global__ void scan1_chunksum(const int* __restrict__ c0, const int* __restrict__ c1,
                               const int* __restrict__ c2, int* __restrict__ csum) {
    int c = blockIdx.x, t = threadIdx.x;
    const int* src; int lc;
    if (c < 200) { src = c0; lc = c; }
    else if (c < 240) { src = c1; lc = c - 200; }
    else { src = c2; lc = c - 240; }
    int v = src[lc * 256 + t];
#pragma unroll
    for (int off = 32; off > 0; off >>= 1) v += __shfl_xor(v, off, 64);
    __shared__ int wsum[4];
    if ((t & 63) == 0) wsum[t >> 6] = v;
    __syncthreads();
    if (t == 0) csum[c] = wsum[0] + wsum[1] + wsum[2] + wsum[3];
}

__global__ void scan2_chunkbase(int* __restrict__ csum, int* __restrict__ o0,
                                int* __restrict__ o1, int* __restrict__ o2) {
    int seg = blockIdx.x, t = threadIdx.x;
    int base = (seg == 0) ? 0 : (seg == 1) ? 200 : 240;
    int nc = (seg == 1) ? 40 : 200;
    __shared__ int sd[256];
    int v = (t < nc) ? csum[base + t] : 0;
    sd[t] = v;
    __syncthreads();
    for (int d = 1; d < 256; d <<= 1) {
        int x = (t >= d) ? sd[t - d] : 0;
        __syncthreads();
        sd[t] += x;
        __syncthreads();
    }
    if (t < nc) csum[base + t] = sd[t] - v;     // exclusive chunk base
    if (t == 255) {
        int total = sd[255];
        if (seg == 0) o0[N_NODES] = total;
        else if (seg == 1) o1[N_HEDGES] = total;
        else o2[N_NODES] = total;
    }
}

__global__ void scan3_writeoff(const int* __restrict__ c0, const int* __restrict__ c1,
                               const int* __restrict__ c2, const int* __restrict__ csum,
                               int* __restrict__ o0, int* __restrict__ o1, int* __restrict__ o2) {
    int c = blockIdx.x, t = threadIdx.x;
    const int* src; int* dst; int lc;
    if (c < 200) { src = c0; dst = o0; lc = c; }
    else if (c < 240) { src = c1; dst = o1; lc = c - 200; }
    else { src = c2; dst = o2; lc = c - 240; }
    int i = lc * 256 + t;
    int v = src[i];
    __shared__ int sd[256];
    sd[t] = v;
    __syncthreads();
    for (int d = 1; d < 256; d <<= 1) {
        int x = (t >= d) ? sd[t - d] : 0;
        __syncthreads();
        sd[t] += x;
        __syncthreads();
    }
    dst[i] = csum[c] + sd[t] - v;
}

__global__ void place_pay(const int* __restrict__ keys, const int* __restrict__ payload,
                          int* __restrict__ cursor, int* __restrict__ pay, int n) {
    int i = blockIdx.x * 256 + threadIdx.x;
    if (i < n) {
        int p = atomicAdd(&cursor[keys[i]], 1);
        pay[p] = payload[i];
    }
}

// ---------------- CSR gather, float4-vectorized (f64 reg accumulation -> replay-stable) ----------------
template<bool SELF, bool SCALE, bool DINV>
__global__ void gather_rows4(const float* __restrict__ src,
                             const int* __restrict__ off, const int* __restrict__ pay,
                             const float* __restrict__ self_src,
                             const int* __restrict__ degoff, const float* __restrict__ tbias,
                             float* __restrict__ out, int R, int F4) {
    int i = blockIdx.x * 256 + threadIdx.x;
    if (i >= R * F4) return;
    int r = i / F4, f4 = i - r * F4;
    int b = off[r], e = off[r + 1];
    double a0 = 0.0, a1 = 0.0, a2 = 0.0, a3 = 0.0;
    for (int j = b; j < e; j++) {
        int p = pay[j];
        float4 v = *((const float4*)(src + (size_t)p * F4 * 4) + f4);
        if (DINV) {
            int d = degoff[p + 1] - degoff[p];
            float inv = d > 0 ? 1.f / d : 0.f;
            a0 += (double)(v.x * inv); a1 += (double)(v.y * inv);
            a2 += (double)(v.z * inv); a3 += (double)(v.w * inv);
        } else {
            a0 += v.x; a1 += v.y; a2 += v.z; a3 += v.w;
        }
    }
    float s0 = (float)a0, s1 = (float)a1, s2 = (float)a2, s3 = (float)a3;
    int cnt = e - b;
    if (DINV) {
        float4 bv = *((const float4*)tbias + f4);
        s0 += cnt * bv.x; s1 += cnt * bv.y; s2 += cnt * bv.z; s3 += cnt * bv.w;
    }
    if (SCALE) {
        float inv = 1.f / fmaxf((float)cnt, 1.f);
        s0 *= inv; s1 *= inv; s2 *= inv; s3 *= inv;
    }
    if (SELF) {
        float4 sv = *((const float4*)self_src + i);
        s0 += sv.x; s1 += sv.y; s2 += sv.z; s3 += sv.w;
    }
    float4 o = {s0, s1, s2, s3};
    *((float4*)out + i) = o;
}

// ---------------- small-K GEMM: C[M,N] f32 = act(A[M,K] f32 @ Wbf[N,KP]^T + b) ----------------
template<bool RELU, int KP>
__global__ __launch_bounds__(256) void gemm_smallk(const float* __restrict__ A,
                                                   const unsigned short* __restrict__ Wbf,
                                                   const float* __restrict__ bias,
                                                   float* __restrict__ C,
                                                   int M, int N, int K) {
    __shared__ __align__(16) char Ab[64 * KP * 2];
    const int tid = threadIdx.x;
    const int bm = blockIdx.x * 64;
    const int wid = tid >> 6, lane = tid & 63;
    const int lr = lane & 15, lg = lane >> 4;
    constexpr int NKK = KP / 32;
    constexpr int CHUNKS = 64 * (KP / 4);

    for (int u = tid; u < CHUNKS; u += 256) {
        int row = u / (KP / 4);
        int kq = (u % (KP / 4)) * 4;
        int off = (row * (KP * 2) + kq * 2) ^ ((row & 7) << 4);
        short4_t sv = {0, 0, 0, 0};
        int gm = bm + row;
        if (gm < M && kq + 4 <= K) {
            float4 f = *(const float4*)(A + (size_t)gm * K + kq);
            sv[0] = (short)f2bf(f.x); sv[1] = (short)f2bf(f.y);
            sv[2] = (short)f2bf(f.z); sv[3] = (short)f2bf(f.w);
        }
        *(short4_t*)(Ab + off) = sv;
    }
    __syncthreads();

    bf16x8 af[NKK];
#pragma unroll
    for (int kk = 0; kk < NKK; kk++) {
        int row = wid * 16 + lr;
        af[kk] = *(const bf16x8*)(Ab + ((row * (KP * 2) + kk * 64 + lg * 16) ^ ((row & 7) << 4)));
    }

    for (int n0 = 0; n0 < N; n0 += 16) {
        int wrow = n0 + lr;
        bf16x8 bf[NKK];
#pragma unroll
        for (int kk = 0; kk < NKK; kk++) {
            uint4 raw = {0u, 0u, 0u, 0u};
            if (wrow < N) raw = *(const uint4*)(Wbf + (size_t)wrow * KP + kk * 32 + lg * 8);
            bf[kk] = __builtin_bit_cast(bf16x8, raw);
        }
        f32x4 acc = {0.f, 0.f, 0.f, 0.f};
#pragma unroll
        for (int kk = 0; kk < NKK; kk++)
            acc = __builtin_amdgcn_mfma_f32_16x16x32_bf16(af[kk], bf[kk], acc, 0, 0, 0);
        int col = n0 + lr;
        if (col < N) {
            float bv = bias ? bias[col] : 0.f;
#pragma unroll
            for (int r = 0; r < 4; r++) {
                int row = bm + wid * 16 + lg * 4 + r;
                if (row < M) {
                    float v = acc[r] + bv;
                    if (RELU) v = fmaxf(v, 0.f);
                    C[(size_t)row * N + col] = v;
                }
            }
        }
    }
}

// ---------------- bf16 GEMM 128x128, BK=64, global_load_lds staging; optional grid.z split-K ----------------
template<bool PARTIAL>
__global__ __launch_bounds__(256) void gemm_bf16(const unsigned short* __restrict__ A,
                                                 const unsigned short* __restrict__ B,
                                                 unsigned short* __restrict__ C,
                                                 float* __restrict__ Cp,
                                                 int M, int N, int K, int kchunk) {
    __shared__ __align__(16) char Asm[16384];   // 128 x 64 bf16, swizzled view on read
    __shared__ __align__(16) char Bsm[16384];
    const int tid = threadIdx.x;
    const int nwg = gridDim.x * gridDim.y;
    const int wg = xcd_swizzle(blockIdx.y * gridDim.x + blockIdx.x, nwg);
    const int bm = (wg % gridDim.y) * 128, bn = (wg / gridDim.y) * 128;
    const int wid = tid >> 6, lane = tid & 63;
    const int wm = (wid >> 1) * 64, wn = (wid & 1) * 64;
    const int lr = lane & 15, lg = lane >> 4;
    const int kbeg = blockIdx.z * kchunk;
    const int kend = min(K, kbeg + kchunk);

    f32x4 zero = {0.f, 0.f, 0.f, 0.f};
    f32x4 acc[4][4];
#pragma unroll
    for (int i = 0; i < 4; i++)
#pragma unroll
        for (int j = 0; j < 4; j++) acc[i][j] = zero;

    for (int k0 = kbeg; k0 < kend; k0 += 64) {
#pragma unroll
        for (int u = 0; u < 4; u++) {
            int blk = wid * 4 + u;               // 0..15 (1KB LDS blocks)
            int row = blk * 8 + (lane >> 3);     // 8 rows per block
            int ch  = (lane & 7) ^ (row & 7);    // inverse swizzle on source
            const unsigned short* gA = A + (size_t)(bm + row) * K + k0 + ch * 8;
            __builtin_amdgcn_global_load_lds(
                (const __attribute__((address_space(1))) unsigned int*)gA,
                (__attribute__((address_space(3))) unsigned int*)(Asm + blk * 1024),
                16, 0, 0);
            const unsigned short* gB = B + (size_t)(bn + row) * K + k0 + ch * 8;
            __builtin_amdgcn_global_load_lds(
                (const __attribute__((address_space(1))) unsigned int*)gB,
                (__attribute__((address_space(3))) unsigned int*)(Bsm + blk * 1024),
                16, 0, 0);
        }
        __syncthreads();
#pragma unroll
        for (int kk = 0; kk < 2; kk++) {
            bf16x8 af[4], bf[4];
#pragma unroll
            for (int m = 0; m < 4; m++) {
                int row = wm + m * 16 + lr;
                af[m] = *(const bf16x8*)(Asm + ((row * 128 + kk * 64 + lg * 16) ^ ((row & 7) << 4)));
            }
#pragma unroll
            for (int n = 0; n < 4; n++) {
                int row = wn + n * 16 + lr;
                bf[n] = *(const bf16x8*)(Bsm + ((row * 128 + kk * 64 + lg * 16) ^ ((row & 7) << 4)));
            }
#pragma unroll
            for (int m = 0; m < 4; m++)
#pragma unroll
                for (int n = 0; n < 4; n++)
                    acc[m][n] = __builtin_amdgcn_mfma_f32_16x16x32_bf16(af[m], bf[n], acc[m][n], 0, 0, 0);
        }
        __syncthreads();
    }
#pragma unroll
    for (int m = 0; m < 4; m++)
#pragma unroll
        for (int n = 0; n < 4; n++) {
            int col = bn + wn + n * 16 + lr;
#pragma unroll
            for (int r = 0; r < 4; r++) {
                int row = bm + wm + m * 16 + lg * 4 + r;
                if (PARTIAL)
                    Cp[(size_t)blockIdx.z * M * N + (size_t)row * N + col] = acc[m][n][r];
                else
                    C[(size_t)row * N + col] = f2bf(acc[m][n][r]);
            }
        }
}

// ---------------- MFMA GEMM 64x64, wave-K-split, reg-prefetch, 32KB LDS, grid.z split-K ----------------
template<bool RELU, bool PARTIAL, typename TA, typename TW>
__global__ __launch_bounds__(256) void gemm64(const TA* __restrict__ A,
                                              const TW* __restrict__ W,
                                              const float* __restrict__ bias,
                                              float* __restrict__ C,
                                              int M, int N, int K, int kchunk) {
    __shared__ __align__(16) char pool[32768];
    char* Ab = pool;
    char* Bb = pool + 16384;
    const int tid = threadIdx.x;
    const int nwg = gridDim.x * gridDim.y;
    const int wg = xcd_swizzle(blockIdx.y * gridDim.x + blockIdx.x, nwg);
    const int bm = (wg / gridDim.x) * 64, bn = (wg % gridDim.x) * 64;
    const int wid = tid >> 6, lane = tid & 63;
    const int lr = lane & 15, lg = lane >> 4;
    const int kbeg = blockIdx.z * kchunk;
    const int kend = min(K, kbeg + kchunk);
    const bool kvec = ((K & 3) == 0);

    f32x4 zero = {0.f, 0.f, 0.f, 0.f};
    f32x4 acc[4][4];
#pragma unroll
    for (int i = 0; i < 4; i++)
#pragma unroll
        for (int j = 0; j < 4; j++) acc[i][j] = zero;

    uint4 ra16[4], rb16[4];
    short4_t ra4[8], rb4[8];

    auto load_A = [&](int kc2) {
        if constexpr (sizeof(TA) == 2) {
#pragma unroll
            for (int u = 0; u < 4; u++) {
                int s = u * 256 + tid;
                int row = s >> 4, k8 = (s & 15) << 3;
                int gk = kc2 + k8, gm = bm + row;
                uint4 v = {0u, 0u, 0u, 0u};
                if (gm < M && gk + 8 <= kend) {
                    v = *(const uint4*)((const unsigned short*)A + (size_t)gm * K + gk);
                } else if (gm < M && gk < kend) {
                    unsigned short tmp[8];
#pragma unroll
                    for (int e = 0; e < 8; e++)
                        tmp[e] = (gk + e < kend) ? ((const unsigned short*)A)[(size_t)gm * K + gk + e] : 0;
                    v = *(const uint4*)tmp;
                }
                ra16[u] = v;
            }
        } else {
#pragma unroll
            for (int u = 0; u < 8; u++) {
                int s = u * 256 + tid;
                int row = s >> 5, kq = (s & 31) << 2;
                int gk = kc2 + kq, gm = bm + row;
                short4_t sv = {0, 0, 0, 0};
                if (gm < M && gk < kend)
                    sv = ld4bf_f32((const float*)A + (size_t)gm * K + gk, gk, kend, kvec);
                ra4[u] = sv;
            }
        }
    };
    auto load_B = [&](int kc2) {
        if constexpr (sizeof(TW) == 2) {
#pragma unroll
            for (int u = 0; u < 4; u++) {
                int s = u * 256 + tid;
                int row = s >> 4, k8 = (s & 15) << 3;
                int gk = kc2 + k8, gn = bn + row;
                uint4 v = {0u, 0u, 0u, 0u};
                if (gn < N && gk + 8 <= kend) {
                    v = *(const uint4*)((const unsigned short*)W + (size_t)gn * K + gk);
                } else if (gn < N && gk < kend) {
                    unsigned short tmp[8];
#pragma unroll
                    for (int e = 0; e < 8; e++)
                        tmp[e] = (gk + e < kend) ? ((const unsigned short*)W)[(size_t)gn * K + gk + e] : 0;
                    v = *(const uint4*)tmp;
                }
                rb16[u] = v;
            }
        } else {
#pragma unroll
            for (int u = 0; u < 8; u++) {
                int s = u * 256 + tid;
                int row = s >> 5, kq = (s & 31) << 2;
                int gk = kc2 + kq, gn = bn + row;
                short4_t sv = {0, 0, 0, 0};
                if (gn < N && gk < kend)
                    sv = ld4bf_f32((const float*)W + (size_t)gn * K + gk, gk, kend, kvec);
                rb4[u] = sv;
            }
        }
    };
    auto write_A = [&]() {
        if constexpr (sizeof(TA) == 2) {
#pragma unroll
            for (int u = 0; u < 4; u++) {
                int s = u * 256 + tid;
                int row = s >> 4, k8 = (s & 15) << 3;
                int off = (row * 256 + k8 * 2) ^ ((row & 7) << 4);
                *(uint4*)(Ab + off) = ra16[u];
            }
        } else {
#pragma unroll
            for (int u = 0; u < 8; u++) {
                int s = u * 256 + tid;
                int row = s >> 5, kq = (s & 31) << 2;
                int off = (row * 256 + kq * 2) ^ ((row & 7) << 4);
                *(short4_t*)(Ab + off) = ra4[u];
            }
        }
    };
    auto write_B = [&]() {
        if constexpr (sizeof(TW) == 2) {
#pragma unroll
            for (int u = 0; u < 4; u++) {
                int s = u * 256 + tid;
                int row = s >> 4, k8 = (s & 15) << 3;
                int off = (row * 256 + k8 * 2) ^ ((row & 7) << 4);
                *(uint4*)(Bb + off) = rb16[u];
            }
        } else {
#pragma unroll
            for (int u = 0; u < 8; u++) {
                int s = u * 256 + tid;
                int row = s >> 5, kq = (s & 31) << 2;
                int off = (row * 256 + kq * 2) ^ ((row & 7) << 4);
                *(short4_t*)(Bb + off) = rb4[u];
            }
        }
    };

    load_A(kbeg);
    load_B(kbeg);
    for (int kc = kbeg; kc < kend; kc += 128) {
        write_A();
        write_B();
        __syncthreads();
        if (kc + 128 < kend) { load_A(kc + 128); load_B(kc + 128); }

        bf16x8 af[4], bf[4];
        const int kb = wid * 64 + lg * 16;
#pragma unroll
        for (int m = 0; m < 4; m++) {
            int row = m * 16 + lr;
            af[m] = *(const bf16x8*)(Ab + ((row * 256 + kb) ^ ((row & 7) << 4)));
        }
#pragma unroll
        for (int n = 0; n < 4; n++) {
            int row = n * 16 + lr;
            bf[n] = *(const bf16x8*)(Bb + ((row * 256 + kb) ^ ((row & 7) << 4)));
        }
#pragma unroll
        for (int m = 0; m < 4; m++)
#pragma unroll
            for (int n = 0; n < 4; n++)
                acc[m][n] = __builtin_amdgcn_mfma_f32_16x16x32_bf16(af[m], bf[n], acc[m][n], 0, 0, 0);
        __syncthreads();
    }

    float* redA = (float*)pool;
    float* redB = (float*)(pool + 16384);
    if (wid < 2) {
        float* r = (wid == 0) ? redA : redB;
#pragma unroll
        for (int m = 0; m < 4; m++)
#pragma unroll
            for (int n = 0; n < 4; n++)
#pragma unroll
                for (int r4 = 0; r4 < 4; r4++)
                    r[(m * 16 + lg * 4 + r4) * 64 + n * 16 + lr] = acc[m][n][r4];
    }
    __syncthreads();
    if (wid >= 2) {
        float* r = (wid == 2) ? redA : redB;
#pragma unroll
        for (int m = 0; m < 4; m++)
#pragma unroll
            for (int n = 0; n < 4; n++)
#pragma unroll
                for (int r4 = 0; r4 < 4; r4++)
                    r[(m * 16 + lg * 4 + r4) * 64 + n * 16 + lr] += acc[m][n][r4];
    }
    __syncthreads();
#pragma unroll
    for (int u = 0; u < 16; u++) {
        int idx = u * 256 + tid;
        int row = idx >> 6, col = idx & 63;
        int gm = bm + row, gn = bn + col;
        if (gm >= M || gn >= N) continue;
        float s = redA[idx] + redB[idx];
        if (PARTIAL) {
            C[(size_t)blockIdx.z * M * N + (size_t)gm * N + gn] = s;
        } else {
            s += bias ? bias[gn] : 0.f;
            if (RELU) s = fmaxf(s, 0.f);
            C[(size_t)gm * N + gn] = s;
        }
    }
}

template<bool RELU>
__global__ void reduce_partial(const float* __restrict__ part, const float* __restrict__ bias,
                               float* __restrict__ C, int MN, int N, int SK) {
    int i = blockIdx.x * 256 + threadIdx.x;
    if (i >= MN) return;
    float s = 0.f;
    for (int z = 0; z < SK; z++) s += part[(size_t)z * MN + i];
    s += bias ? bias[i % N] : 0.f;
    if (RELU) s = fmaxf(s, 0.f);
    C[i] = s;
}

// reduce + bias (+relu), output either f32 or bf16
template<bool RELU, bool OUTBF>
__global__ void reduce_partial2(const float* __restrict__ part, const float* __restrict__ bias,
                                void* __restrict__ Cv, int MN, int N, int SK) {
    int i = blockIdx.x * 256 + threadIdx.x;
    if (i >= MN) return;
    float s = 0.f;
    for (int z = 0; z < SK; z++) s += part[(size_t)z * MN + i];
    s += bias ? bias[i % N] : 0.f;
    if (RELU) s = fmaxf(s, 0.f);
    if (OUTBF) ((unsigned short*)Cv)[i] = f2bf(s);
    else       ((float*)Cv)[i] = s;
}

// ---------------- cvt W [Nw][K] f32 -> [Nw][Kp] bf16 (zero-padded K) ----------------
__global__ void cvt_w_pad(const float* __restrict__ W, unsigned short* __restrict__ Wb,
                          int Nw, int K, int Kp) {
    int i = blockIdx.x * 256 + threadIdx.x;
    if (i >= Nw * Kp) return;
    int r = i / Kp, k = i - r * Kp;
    Wb[i] = (k < K) ? f2bf(W[(size_t)r * K + k]) : (unsigned short)0;
}

// ---------------- fused GIN2 GEMM + bias + relu + 50-row max/mean pool -> bf16 [1024][1792] ----------------
__global__ __launch_bounds__(256) void gin2pool(const float* __restrict__ xin2,
                                                const unsigned short* __restrict__ Wbf,
                                                const float* __restrict__ bias,
                                                unsigned short* __restrict__ out) {
    __shared__ __align__(16) char Ab[16384];
    const int tid = threadIdx.x;
    const int g = blockIdx.x;
    const int wid = tid >> 6, lane = tid & 63;
    const int lr = lane & 15, lg = lane >> 4;
    const int K = FXD;
    const int N = 840;

#pragma unroll
    for (int u = 0; u < 8; u++) {
        int s = u * 256 + tid;
        int row = s >> 5, kq = (s & 31) << 2;
        int off = (row * 256 + (s & 31) * 8) ^ ((row & 7) << 4);
        float v0 = 0.f, v1 = 0.f, v2 = 0.f, v3 = 0.f;
        if (row < NPG && kq < K) {
            float4 f = *(const float4*)(xin2 + ((size_t)g * NPG + row) * K + kq);
            v0 = f.x; v1 = f.y; v2 = f.z; v3 = f.w;
        }
        short4_t sv;
        sv[0] = (short)f2bf(v0); sv[1] = (short)f2bf(v1);
        sv[2] = (short)f2bf(v2); sv[3] = (short)f2bf(v3);
        *(short4_t*)(Ab + off) = sv;
    }
    __syncthreads();

    bf16x8 af[4][3];
#pragma unroll
    for (int m = 0; m < 4; m++)
#pragma unroll
        for (int kk = 0; kk < 3; kk++) {
            int row = m * 16 + lr;
            af[m][kk] = *(const bf16x8*)(Ab + ((row * 256 + kk * 64 + lg * 16) ^ ((row & 7) << 4)));
        }

    for (int t = 0; t < 14; t++) {
        const int n0 = t * 64 + wid * 16;
        const int wrow = n0 + lr;
        bf16x8 bf[3];
#pragma unroll
        for (int kk = 0; kk < 3; kk++) {
            int k0 = kk * 32 + lg * 8;
            uint4 raw = {0u, 0u, 0u, 0u};
            if (wrow < N) raw = *(const uint4*)(Wbf + (size_t)wrow * 96 + k0);
            bf[kk] = __builtin_bit_cast(bf16x8, raw);
        }
        f32x4 zero = {0.f, 0.f, 0.f, 0.f};
        f32x4 acc[4] = {zero, zero, zero, zero};
#pragma unroll
        for (int m = 0; m < 4; m++)
#pragma unroll
            for (int kk = 0; kk < 3; kk++)
                acc[m] = __builtin_amdgcn_mfma_f32_16x16x32_bf16(af[m][kk], bf[kk], acc[m], 0, 0, 0);

        const int c = n0 + lr;
        float bv = (c < N) ? bias[c] : 0.f;
        float mx = -1e30f, sm = 0.f;
#pragma unroll
        for (int m = 0; m < 4; m++)
#pragma unroll
            for (int r = 0; r < 4; r++) {
                int row = m * 16 + lg * 4 + r;
                if (row < NPG) {
                    float v = fmaxf(acc[m][r] + bv, 0.f);
                    mx = fmaxf(mx, v);
                    sm += v;
                }
            }
        mx = fmaxf(mx, __shfl_xor(mx, 16, 64));
        sm += __shfl_xor(sm, 16, 64);
        mx = fmaxf(mx, __shfl_xor(mx, 32, 64));
        sm += __shfl_xor(sm, 32, 64);
        if (lg == 0 && c < N) {
            out[(size_t)g * 1792 + c] = f2bf(mx);
            out[(size_t)g * 1792 + 840 + c] = f2bf(sm * (1.f / NPG));
        }
    }
    if (tid < 112) out[(size_t)g * 1792 + 1680 + tid] = 0;
}

// ---------------- N=1 GEMM ----------------
__global__ __launch_bounds__(256) void rowdot(const float* __restrict__ A,
                                              const float* __restrict__ w,
                                              const float* __restrict__ b,
                                              float* __restrict__ out, int Mrows, int K) {
    int row = blockIdx.x * 4 + (threadIdx.x >> 6);
    int lane = threadIdx.x & 63;
    if (row >= Mrows) return;
    float s = 0.f;
    for (int k = lane; k < K; k += 64) s += A[(size_t)row * K + k] * w[k];
#pragma unroll
    for (int off = 32; off > 0; off >>= 1) s += __shfl_xor(s, off, 64);
    if (lane == 0) out[row] = s + b[0];
}

// ---------------- fused node-gather + Dinv + bias + 50-row max/mean pool -> bf16 [1024][512] ----------------
// hn2 never materialized: per (graph, float4-col), walk the 50 nodes' CSR buckets
// over e2 directly (f64 accumulate per node -> replay-stable), then pool.
__global__ void pool_hyper_fused(const float* __restrict__ e2,
                                 const int* __restrict__ off_n, const int* __restrict__ pay_n,
                                 const float* __restrict__ b, unsigned short* __restrict__ out) {
    int i = blockIdx.x * 256 + threadIdx.x;   // over 1024 * 64 (float4 cols)
    if (i >= NB * 64) return;
    int o4 = i & 63, g = i >> 6;
    float4 bv = *((const float4*)b + o4);
    float mx0 = -1e30f, mx1 = -1e30f, mx2 = -1e30f, mx3 = -1e30f;
    float sm0 = 0.f, sm1 = 0.f, sm2 = 0.f, sm3 = 0.f;
    for (int n = 0; n < NPG; n++) {
        int node = g * NPG + n;
        int bb = off_n[node], ee = off_n[node + 1];
        double a0 = 0.0, a1 = 0.0, a2 = 0.0, a3 = 0.0;
        for (int j = bb; j < ee; j++) {
            float4 v = *((const float4*)(e2 + (size_t)pay_n[j] * 256) + o4);
            a0 += v.x; a1 += v.y; a2 += v.z; a3 += v.w;
        }
        int d = ee - bb;
        float inv = d > 0 ? 1.f / d : 0.f;
        float v0 = (float)a0 * inv + bv.x;
        float v1 = (float)a1 * inv + bv.y;
        float v2 = (float)a2 * inv + bv.z;
        float v3 = (float)a3 * inv + bv.w;
        mx0 = fmaxf(mx0, v0); sm0 += v0;
        mx1 = fmaxf(mx1, v1); sm1 += v1;
        mx2 = fmaxf(mx2, v2); sm2 += v2;
        mx3 = fmaxf(mx3, v3); sm3 += v3;
    }
    unsigned short* og = out + (size_t)g * 512 + o4 * 4;
    og[0] = f2bf(mx0); og[1] = f2bf(mx1); og[2] = f2bf(mx2); og[3] = f2bf(mx3);
    og[256] = f2bf(sm0 * (1.f / NPG)); og[257] = f2bf(sm1 * (1.f / NPG));
    og[258] = f2bf(sm2 * (1.f / NPG)); og[259] = f2bf(sm3 * (1.f / NPG));
}

// ---------------- pack fusion tokens -> bf16 ----------------
__global__ void pack_tokens_bf(const float* __restrict__ fp_o, const float* __restrict__ xg,
                               const float* __restrict__ hxg, const float* __restrict__ t,
                               unsigned short* __restrict__ in_t) {
    int i = blockIdx.x * 256 + threadIdx.x;
    if (i >= 4096 * 512) return;
    int d = i & 511;
    int row = i >> 9;
    int tok = row & 3, b = row >> 2;
    const float* s = (tok == 0) ? fp_o : (tok == 1) ? xg : (tok == 2) ? hxg : t;
    in_t[i] = f2bf(s[b * 512 + d]);
}

// ---------------- concat + cvt Wq|Wk|Wv -> bf16 [6144][512] ----------------
__global__ void cvt_qkv_w(const float* __restrict__ Wq, const float* __restrict__ Wk,
                          const float* __restrict__ Wv, unsigned short* __restrict__ Wb) {
    int i = blockIdx.x * 256 + threadIdx.x;
    if (i >= 6144 * 512) return;
    int n = i >> 9;
    const float* src = (n < 2048) ? Wq : (n < 4096) ? Wk : Wv;
    int nn = (n < 2048) ? n : (n < 4096) ? n - 2048 : n - 4096;
    Wb[i] = f2bf(src[(size_t)nn * 512 + (i & 511)]);
}

// ---------------- fused attention + conv3x3 + relu -> cbuf bf16 [1024][4096] ----------------
__global__ __launch_bounds__(256) void attn_conv(const unsigned short* __restrict__ QKV,
                                                 const float* __restrict__ cw,
                                                 const float* __restrict__ cb,
                                                 unsigned short* __restrict__ c) {
    __shared__ float att_s[4][4][512];   // [head][token][d] = 32 KB
    __shared__ float w[144];
    __shared__ float bias[4];
    const int tid = threadIdx.x;
    const int wid = tid >> 6, lane = tid & 63;
    const int b = blockIdx.x;
    if (tid < 144) w[tid] = cw[tid];
    if (tid < 4) bias[tid] = cb[tid];

    const unsigned short* qb = QKV + (size_t)b * 4 * 6144 + wid * 512;
    const unsigned short* kb = qb + 2048;
    const unsigned short* vb = qb + 4096;
    float qr[4][8], kr[4][8];
#pragma unroll
    for (int n = 0; n < 4; n++)
#pragma unroll
        for (int cc = 0; cc < 8; cc++) {
            qr[n][cc] = bf2f(qb[n * 6144 + cc * 64 + lane]);
            kr[n][cc] = bf2f(kb[n * 6144 + cc * 64 + lane]);
        }
    float s[4][4];
#pragma unroll
    for (int n = 0; n < 4; n++)
#pragma unroll
        for (int m = 0; m < 4; m++) {
            float p = 0.f;
#pragma unroll
            for (int cc = 0; cc < 8; cc++) p += qr[n][cc] * kr[m][cc];
#pragma unroll
            for (int off = 32; off > 0; off >>= 1) p += __shfl_xor(p, off, 64);
            s[n][m] = p * 0.04419417382415922f;   // 1/sqrt(512)
        }
    float pm[4][4];
#pragma unroll
    for (int n = 0; n < 4; n++) {
        float mx = fmaxf(fmaxf(s[n][0], s[n][1]), fmaxf(s[n][2], s[n][3]));
        float e0 = expf(s[n][0] - mx), e1 = expf(s[n][1] - mx);
        float e2 = expf(s[n][2] - mx), e3 = expf(s[n][3] - mx);
        float inv = 1.f / (e0 + e1 + e2 + e3);
        pm[n][0] = e0 * inv; pm[n][1] = e1 * inv; pm[n][2] = e2 * inv; pm[n][3] = e3 * inv;
    }
#pragma unroll
    for (int cc = 0; cc < 8; cc++) {
        float v0 = bf2f(vb[0 * 6144 + cc * 64 + lane]);
        float v1 = bf2f(vb[1 * 6144 + cc * 64 + lane]);
        float v2 = bf2f(vb[2 * 6144 + cc * 64 + lane]);
        float v3 = bf2f(vb[3 * 6144 + cc * 64 + lane]);
#pragma unroll
        for (int n = 0; n < 4; n++)
            att_s[wid][n][cc * 64 + lane] = pm[n][0] * v0 + pm[n][1] * v1 + pm[n][2] * v2 + pm[n][3] * v3;
    }
    __syncthreads();

    for (int it = 0; it < 16; it++) {
        int j = it * 256 + tid;            // 0..4095
        float v = 0.f;
        if (j < 4080) {
            int wo = j % 510;
            int r = j / 510;
            int ho = r & 1, co = r >> 1;
            float acc = bias[co];
#pragma unroll
            for (int ci = 0; ci < 4; ci++)
#pragma unroll
                for (int kh = 0; kh < 3; kh++)
#pragma unroll
                    for (int kw = 0; kw < 3; kw++)
                        acc += att_s[ci][ho + kh][wo + kw] * w[((co * 4 + ci) * 3 + kh) * 3 + kw];
            v = fmaxf(acc, 0.f);
        }
        c[(size_t)b * 4096 + j] = f2bf(v);
    }
}

// ---------------- host side ----------------
template<typename TA, typename TW>
static inline void launch_gemm64(const TA* A, const TW* W, const float* b, float* C,
                                 int M, int N, int K, bool relu, float* part, hipStream_t s) {
    int gx = (N + 63) / 64, gy = (M + 63) / 64;
    int targetSK = 1024 / (gx * gy);
    if (targetSK < 1) targetSK = 1;
    if (targetSK > 8) targetSK = 8;
    int kchunk = K, SK = 1;
    if (targetSK > 1) {
        kchunk = (((K + targetSK - 1) / targetSK) + 127) & ~127;
        SK = (K + kchunk - 1) / kchunk;
    }
    if (SK <= 1) {
        dim3 g(gx, gy);
        if (relu) gemm64<true, false, TA, TW><<<g, 256, 0, s>>>(A, W, b, C, M, N, K, K);
        else      gemm64<false, false, TA, TW><<<g, 256, 0, s>>>(A, W, b, C, M, N, K, K);
    } else {
        dim3 g(gx, gy, SK);
        gemm64<false, true, TA, TW><<<g, 256, 0, s>>>(A, W, nullptr, part, M, N, K, kchunk);
        int MN = M * N;
        if (relu) reduce_partial<true><<<(MN + 255) / 256, 256, 0, s>>>(part, b, C, MN, N, SK);
        else      reduce_partial<false><<<(MN + 255) / 256, 256, 0, s>>>(part, b, C, MN, N, SK);
    }
}

extern "C" void kernel_launch(void* const* d_in, const int* in_sizes, int n_in,
                              void* d_out, int out_size, void* d_ws, size_t ws_size,
                              hipStream_t stream) {
    const float* x       = (const float*)d_in[0];
    const int*   edge    = (const int*)d_in[1];
    const int*   hedge   = (const int*)d_in[3];
    const float* fp      = (const float*)d_in[4];
    const float* text_em = (const float*)d_in[5];
    const float* fc1_W = (const float*)d_in[7];  const float* fc1_b = (const float*)d_in[8];
    const float* fc2_W = (const float*)d_in[9];  const float* fc2_b = (const float*)d_in[10];
    const float* fc3_W = (const float*)d_in[11]; const float* fc3_b = (const float*)d_in[12];
    const float* fcg1_W = (const float*)d_in[13]; const float* fcg1_b = (const float*)d_in[14];
    const float* fcg2_W = (const float*)d_in[15]; const float* fcg2_b = (const float*)d_in[16];
    const float* fchg1_W = (const float*)d_in[17]; const float* fchg1_b = (const float*)d_in[18];
    const float* fchg2_W = (const float*)d_in[19]; const float* fchg2_b = (const float*)d_in[20];
    const float* gin1_W = (const float*)d_in[21]; const float* gin1_b = (const float*)d_in[22];
    const float* gin2_W = (const float*)d_in[23]; const float* gin2_b = (const float*)d_in[24];
    const float* h3_W = (const float*)d_in[25]; const float* h3_b = (const float*)d_in[26];
    const float* h4_W = (const float*)d_in[27]; const float* h4_b = (const float*)d_in[28];
    const float* Wq = (const float*)d_in[29];
    const float* Wk = (const float*)d_in[30];
    const float* Wv = (const float*)d_in[31];
    const float* conv_W = (const float*)d_in[32]; const float* conv_b = (const float*)d_in[33];
    const float* mlp1_W = (const float*)d_in[34]; const float* mlp1_b = (const float*)d_in[35];
    const float* mlp2_W = (const float*)d_in[36]; const float* mlp2_b = (const float*)d_in[37];

    const int* e_src = edge;
    const int* e_dst = edge + N_EDGES;
    const int* h_nid = hedge;
    const int* h_eid = hedge + N_HNNZ;

    float* ws = (float*)d_ws;
    const size_t ZONE = 51609600;
    // ---- phase A (GIN) ----
    float* xin1 = ws;                               // 4,300,800
    float* xg1  = ws + 4300800;                     // 4,300,800
    float* xin2 = ws + 8601600;                     // 4,300,800
    // ---- phase H (hypergraph) ----
    float* eagg   = ws;                             // 860,160
    float* e1_32  = ws + 860160;                    // 1,720,320
    float* hnode  = ws + 2580480;                   // 8,601,600
    float* eagg2  = ws + 19783680;                  // 1,720,320
    float* e2_32  = ws + 21504000;                  // 2,621,440 (ends 24,125,440)
    // ---- phase D (attention) ----
    unsigned short* in_t_bf  = (unsigned short*)ws;                 // 2,097,152 us
    unsigned short* qkv_bf   = (unsigned short*)(ws + 2097152);     // 25,165,824 us
    unsigned short* cbuf_bf  = (unsigned short*)(ws + 35651584);    // 4,194,304 us (1024x4096)
    float* m1   = ws + 39829504;                                    // 1,048,576
    unsigned short* Wqkv_bf  = (unsigned short*)(ws + 40878080);    // 3,145,728 us
    unsigned short* mlp1W_bf = (unsigned short*)(ws + 42450944);    // 4,194,304 us (ends 44,548,096)
    float* part = ws;                               // split-K partial scratch (zone-dead windows)
    // ---- CSR + weight-cvt region (above phase high-water marks, inside ZONE) ----
    int* cnt_g = (int*)(ws + 45000000);
    int* off_g = (int*)(ws + 45051200);
    int* pay_g = (int*)(ws + 45102401);
    int* cnt_e = (int*)(ws + 45307201);
    int* off_e = (int*)(ws + 45317441);
    int* pay_e = (int*)(ws + 45327682);
    int* cnt_n = (int*)(ws + 45430082);
    int* off_n = (int*)(ws + 45481282);
    int* pay_n = (int*)(ws + 45532483);             // ends 45,634,883
    int* csum  = (int*)(ws + 45650000);             // 440 ints
    unsigned short* gin2Wbf  = (unsigned short*)(ws + 45700000);    // 80,640 us
    unsigned short* fcg1Wbf  = (unsigned short*)(ws + 45800000);    // 1,835,008 us
    unsigned short* fcg2Wbf  = (unsigned short*)(ws + 46750000);    // 524,288 us
    unsigned short* fchg1Wbf = (unsigned short*)(ws + 47050000);    // 524,288 us
    unsigned short* fchg2Wbf = (unsigned short*)(ws + 47350000);    // 524,288 us
    unsigned short* gin1Wbf  = (unsigned short*)(ws + 47700000);    // 84x96 us
    unsigned short* h3Wbf    = (unsigned short*)(ws + 47750000);    // 168x96 us
    unsigned short* h4Wbf    = (unsigned short*)(ws + 47800000);    // 256x192 us
    unsigned short* fp_bf    = (unsigned short*)(ws + 48000000);    // 1024x2560 us
    unsigned short* text_bf  = (unsigned short*)(ws + 49350000);    // 1024x768 us
    unsigned short* fc1Wbf   = (unsigned short*)(ws + 49800000);    // 128x2560 us
    unsigned short* fc3Wbf   = (unsigned short*)(ws + 50000000);    // 512x768 us (ends < ZONE)
    // ---- persistent ----
    unsigned short* xg_raw_bf = (unsigned short*)(ws + ZONE);           // 1024x1792 us
    unsigned short* xg_mid_bf = (unsigned short*)(ws + ZONE + 1720320); // 1024x1024 us
    unsigned short* hx_raw_bf = (unsigned short*)(ws + ZONE + 2768896); // 1024x512 us
    unsigned short* hx_mid_bf = (unsigned short*)(ws + ZONE + 3293184); // 1024x1024 us
    float* h1     = ws + ZONE + 4341760;
    float* fp_o   = ws + ZONE + 4472832;
    float* tt     = ws + ZONE + 4997120;
    const size_t NEED = (ZONE + 5582848) * sizeof(float);
    if (ws_size < NEED) return;

    float* out_y  = (float*)d_out;
    float* xg_out = out_y + 1024;
    float* hx_out = out_y + 1024 + 1024 * 512;

    // ---------- build 3 CSR structures (parallel scan) + weight/input converts ----------
    hipMemsetAsync(cnt_g, 0, N_NODES * 4, stream);
    hipMemsetAsync(cnt_e, 0, N_HEDGES * 4, stream);
    hipMemsetAsync(cnt_n, 0, N_NODES * 4, stream);
    histo_i<<<(N_EDGES + 255) / 256, 256, 0, stream>>>(e_dst, cnt_g, N_EDGES);
    histo_i<<<(N_HNNZ + 255) / 256, 256, 0, stream>>>(h_eid, cnt_e, N_HNNZ);
    histo_i<<<(N_HNNZ + 255) / 256, 256, 0, stream>>>(h_nid, cnt_n, N_HNNZ);
    scan1_chunksum<<<440, 256, 0, stream>>>(cnt_g, cnt_e, cnt_n, csum);
    scan2_chunkbase<<<3, 256, 0, stream>>>(csum, off_g, off_e, off_n);
    scan3_writeoff<<<440, 256, 0, stream>>>(cnt_g, cnt_e, cnt_n, csum, off_g, off_e, off_n);
    hipMemcpyAsync(cnt_g, off_g, N_NODES * 4, hipMemcpyDeviceToDevice, stream);
    hipMemcpyAsync(cnt_e, off_e, N_HEDGES * 4, hipMemcpyDeviceToDevice, stream);
    hipMemcpyAsync(cnt_n, off_n, N_NODES * 4, hipMemcpyDeviceToDevice, stream);
    place_pay<<<(N_EDGES + 255) / 256, 256, 0, stream>>>(e_dst, e_src, cnt_g, pay_g, N_EDGES);
    place_pay<<<(N_HNNZ + 255) / 256, 256, 0, stream>>>(h_eid, h_nid, cnt_e, pay_e, N_HNNZ);
    place_pay<<<(N_HNNZ + 255) / 256, 256, 0, stream>>>(h_nid, h_eid, cnt_n, pay_n, N_HNNZ);
    cvt_w_pad<<<(840 * 96 + 255) / 256, 256, 0, stream>>>(gin2_W, gin2Wbf, 840, 84, 96);
    cvt_w_pad<<<(1024 * 1792 + 255) / 256, 256, 0, stream>>>(fcg1_W, fcg1Wbf, 1024, 1680, 1792);
    cvt_w_pad<<<(512 * 1024 + 255) / 256, 256, 0, stream>>>(fcg2_W, fcg2Wbf, 512, 1024, 1024);
    cvt_w_pad<<<(1024 * 512 + 255) / 256, 256, 0, stream>>>(fchg1_W, fchg1Wbf, 1024, 512, 512);
    cvt_w_pad<<<(512 * 1024 + 255) / 256, 256, 0, stream>>>(fchg2_W, fchg2Wbf, 512, 1024, 1024);
    cvt_w_pad<<<(84 * 96 + 255) / 256, 256, 0, stream>>>(gin1_W, gin1Wbf, 84, 84, 96);
    cvt_w_pad<<<(168 * 96 + 255) / 256, 256, 0, stream>>>(h3_W, h3Wbf, 168, 84, 96);
    cvt_w_pad<<<(256 * 192 + 255) / 256, 256, 0, stream>>>(h4_W, h4Wbf, 256, 168, 192);
    cvt_w_pad<<<(1024 * 2560 + 255) / 256, 256, 0, stream>>>(fp, fp_bf, 1024, 2513, 2560);
    cvt_w_pad<<<(128 * 2560 + 255) / 256, 256, 0, stream>>>(fc1_W, fc1Wbf, 128, 2513, 2560);
    cvt_w_pad<<<(1024 * 768 + 255) / 256, 256, 0, stream>>>(text_em, text_bf, 1024, 768, 768);
    cvt_w_pad<<<(512 * 768 + 255) / 256, 256, 0, stream>>>(fc3_W, fc3Wbf, 512, 768, 768);

    // ---------- GIN branch ----------
    gather_rows4<true, false, false><<<(N_NODES * (FXD / 4) + 255) / 256, 256, 0, stream>>>(
        x, off_g, pay_g, x, nullptr, nullptr, xin1, N_NODES, FXD / 4);
    gemm_smallk<true, 96><<<N_NODES / 64, 256, 0, stream>>>(xin1, gin1Wbf, gin1_b, xg1, N_NODES, FXD, FXD);
    gather_rows4<true, false, false><<<(N_NODES * (FXD / 4) + 255) / 256, 256, 0, stream>>>(
        xg1, off_g, pay_g, xg1, nullptr, nullptr, xin2, N_NODES, FXD / 4);
    gin2pool<<<NB, 256, 0, stream>>>(xin2, gin2Wbf, gin2_b, xg_raw_bf);
    gemm_bf16<true><<<dim3(8, 8, 7), 256, 0, stream>>>(
        xg_raw_bf, fcg1Wbf, nullptr, part, 1024, 1024, 1792, 256);
    reduce_partial2<true, true><<<(1024 * 1024 + 255) / 256, 256, 0, stream>>>(
        part, fcg1_b, xg_mid_bf, 1024 * 1024, 1024, 7);
    gemm_bf16<true><<<dim3(4, 8, 8), 256, 0, stream>>>(
        xg_mid_bf, fcg2Wbf, nullptr, part, 1024, 512, 1024, 128);
    reduce_partial2<false, false><<<(1024 * 512 + 255) / 256, 256, 0, stream>>>(
        part, fcg2_b, xg_out, 1024 * 512, 512, 8);

    // ---------- hypergraph branch ----------
    gather_rows4<false, true, false><<<(N_HEDGES * (FXD / 4) + 255) / 256, 256, 0, stream>>>(
        x, off_e, pay_e, nullptr, nullptr, nullptr, eagg, N_HEDGES, FXD / 4);
    gemm_smallk<false, 96><<<N_HEDGES / 64, 256, 0, stream>>>(eagg, h3Wbf, nullptr, e1_32, N_HEDGES, 168, FXD);
    gather_rows4<false, false, false><<<(N_NODES * 42 + 255) / 256, 256, 0, stream>>>(
        e1_32, off_n, pay_n, nullptr, nullptr, nullptr, hnode, N_NODES, 42);
    gather_rows4<false, true, true><<<(N_HEDGES * 42 + 255) / 256, 256, 0, stream>>>(
        hnode, off_e, pay_e, nullptr, off_n, h3_b, eagg2, N_HEDGES, 42);
    gemm_smallk<false, 192><<<N_HEDGES / 64, 256, 0, stream>>>(eagg2, h4Wbf, nullptr, e2_32, N_HEDGES, 256, 168);
    // fused: node-gather over e2 + Dinv + bias + pool (hn2 never materialized)
    pool_hyper_fused<<<(NB * 64 + 255) / 256, 256, 0, stream>>>(e2_32, off_n, pay_n, h4_b, hx_raw_bf);
    gemm_bf16<true><<<dim3(8, 8, 4), 256, 0, stream>>>(
        hx_raw_bf, fchg1Wbf, nullptr, part, 1024, 1024, 512, 128);
    reduce_partial2<true, true><<<(1024 * 1024 + 255) / 256, 256, 0, stream>>>(
        part, fchg1_b, hx_mid_bf, 1024 * 1024, 1024, 4);
    gemm_bf16<true><<<dim3(4, 8, 8), 256, 0, stream>>>(
        hx_mid_bf, fchg2Wbf, nullptr, part, 1024, 512, 1024, 128);
    reduce_partial2<false, false><<<(1024 * 512 + 255) / 256, 256, 0, stream>>>(
        part, fchg2_b, hx_out, 1024 * 512, 512, 8);

    // ---------- fingerprint + text (bf16 padded paths) ----------
    gemm_bf16<true><<<dim3(1, 8, 8), 256, 0, stream>>>(
        fp_bf, fc1Wbf, nullptr, part, 1024, 128, 2560, 320);
    reduce_partial<true><<<(1024 * 128 + 255) / 256, 256, 0, stream>>>(
        part, fc1_b, h1, 1024 * 128, 128, 8);
    launch_gemm64(h1, fc2_W, fc2_b, fp_o, NB, HID, FP2, false, part, stream);
    gemm_bf16<true><<<dim3(4, 8, 4), 256, 0, stream>>>(
        text_bf, fc3Wbf, nullptr, part, 1024, 512, 768, 192);
    reduce_partial2<false, false><<<(1024 * 512 + 255) / 256, 256, 0, stream>>>(
        part, fc3_b, tt, 1024 * 512, 512, 4);

    // ---------- fusion attention (bf16 pipeline) ----------
    pack_tokens_bf<<<(4096 * 512 + 255) / 256, 256, 0, stream>>>(fp_o, xg_out, hx_out, tt, in_t_bf);
    cvt_qkv_w<<<(6144 * 512 + 255) / 256, 256, 0, stream>>>(Wq, Wk, Wv, Wqkv_bf);
    gemm_bf16<false><<<dim3(6144 / 128, 4096 / 128), 256, 0, stream>>>(
        in_t_bf, Wqkv_bf, qkv_bf, nullptr, 4096, 6144, 512, 512);
    attn_conv<<<NB, 256, 0, stream>>>(qkv_bf, conv_W, conv_b, cbuf_bf);
    cvt_w_pad<<<(1024 * 4096 + 255) / 256, 256, 0, stream>>>(mlp1_W, mlp1W_bf, 1024, 4080, 4096);
    gemm_bf16<true><<<dim3(8, 8, 8), 256, 0, stream>>>(
        cbuf_bf, mlp1W_bf, nullptr, part, 1024, 1024, 4096, 512);
    reduce_partial<true><<<(1024 * 1024 + 255) / 256, 256, 0, stream>>>(
        part, mlp1_b, m1, 1024 * 1024, 1024, 8);
    rowdot<<<256, 256, 0, stream>>>(m1, mlp2_W, mlp2_b, out_y, NB, 1024);
}

// Round 21
// 532.936 us; speedup vs baseline: 1.0689x; 1.0689x over previous
//
#include <hip/hip_runtime.h>
#include <hip/hip_bf16.h>

// ---------------- constants ----------------
#define N_NODES 51200
#define N_EDGES 204800
#define N_HNNZ  102400
#define N_HEDGES 10240
#define NB 1024          // batch (graphs)
#define NPG 50           // nodes per graph (51200/1024)
#define FXD 84
#define FP_DIM 2513
#define FP2 128
#define HID 512

typedef __attribute__((ext_vector_type(4))) float f32x4;
typedef __attribute__((ext_vector_type(8))) __bf16 bf16x8;
typedef __attribute__((ext_vector_type(4))) short short4_t;

static __device__ __forceinline__ unsigned short f2bf(float f) {
    unsigned u = __builtin_bit_cast(unsigned, f);
    u += 0x7FFFu + ((u >> 16) & 1u);   // round-to-nearest-even
    return (unsigned short)(u >> 16);
}
static __device__ __forceinline__ float bf2f(unsigned short u) {
    unsigned x = ((unsigned)u) << 16;
    return __builtin_bit_cast(float, x);
}

// bijective XCD-aware remap (m204 formula)
static __device__ __forceinline__ int xcd_swizzle(int orig, int nwg) {
    int q = nwg >> 3, r = nwg & 7;
    int xcd = orig & 7, off = orig >> 3;
    return (xcd < r ? xcd * (q + 1) : r * (q + 1) + (xcd - r) * q) + off;
}

// load 4 f32 as bf16 short4 with K-guards
static __device__ __forceinline__ short4_t ld4bf_f32(const float* p, int gk, int kend, bool kvec) {
    short4_t sv;
    float v0 = 0.f, v1 = 0.f, v2 = 0.f, v3 = 0.f;
    if (kvec && gk + 4 <= kend) {
        float4 f = *(const float4*)p;
        v0 = f.x; v1 = f.y; v2 = f.z; v3 = f.w;
    } else {
        v0 = p[0];
        if (gk + 1 < kend) v1 = p[1];
        if (gk + 2 < kend) v2 = p[2];
        if (gk + 3 < kend) v3 = p[3];
    }
    sv[0] = (short)f2bf(v0); sv[1] = (short)f2bf(v1);
    sv[2] = (short)f2bf(v2); sv[3] = (short)f2bf(v3);
    return sv;
}

// ---------------- CSR build ----------------
__global__ void histo_i(const int* __restrict__ keys, int* __restrict__ cnt, int n) {
    int i = blockIdx.x * 256 + threadIdx.x;
    if (i < n) atomicAdd(&cnt[keys[i]], 1);
}

// 3-phase parallel exclusive scan over 3 concatenated count arrays.
__global__ void scan1_chunksum(const int* __restrict__ c0, const int* __restrict__ c1,
                               const int* __restrict__ c2, int* __restrict__ csum) {
    int c = blockIdx.x, t = threadIdx.x;
    const int* src; int lc;
    if (c < 200) { src = c0; lc = c; }
    else if (c < 240) { src = c1; lc = c - 200; }
    else { src = c2; lc = c - 240; }
    int v = src[lc * 256 + t];
#pragma unroll
    for (int off = 32; off > 0; off >>= 1) v += __shfl_xor(v, off, 64);
    __shared__ int wsum[4];
    if ((t & 63) == 0) wsum[t >> 6] = v;
    __syncthreads();
    if (t == 0) csum[c] = wsum[0] + wsum[1] + wsum[2] + wsum[3];
}

__global__ void scan2_chunkbase(int* __restrict__ csum, int* __restrict__ o0,
                                int* __restrict__ o1, int* __restrict__ o2) {
    int seg = blockIdx.x, t = threadIdx.x;
    int base = (seg == 0) ? 0 : (seg == 1) ? 200 : 240;
    int nc = (seg == 1) ? 40 : 200;
    __shared__ int sd[256];
    int v = (t < nc) ? csum[base + t] : 0;
    sd[t] = v;
    __syncthreads();
    for (int d = 1; d < 256; d <<= 1) {
        int x = (t >= d) ? sd[t - d] : 0;
        __syncthreads();
        sd[t] += x;
        __syncthreads();
    }
    if (t < nc) csum[base + t] = sd[t] - v;     // exclusive chunk base
    if (t == 255) {
        int total = sd[255];
        if (seg == 0) o0[N_NODES] = total;
        else if (seg == 1) o1[N_HEDGES] = total;
        else o2[N_NODES] = total;
    }
}

__global__ void scan3_writeoff(const int* __restrict__ c0, const int* __restrict__ c1,
                               const int* __restrict__ c2, const int* __restrict__ csum,
                               int* __restrict__ o0, int* __restrict__ o1, int* __restrict__ o2) {
    int c = blockIdx.x, t = threadIdx.x;
    const int* src; int* dst; int lc;
    if (c < 200) { src = c0; dst = o0; lc = c; }
    else if (c < 240) { src = c1; dst = o1; lc = c - 200; }
    else { src = c2; dst = o2; lc = c - 240; }
    int i = lc * 256 + t;
    int v = src[i];
    __shared__ int sd[256];
    sd[t] = v;
    __syncthreads();
    for (int d = 1; d < 256; d <<= 1) {
        int x = (t >= d) ? sd[t - d] : 0;
        __syncthreads();
        sd[t] += x;
        __syncthreads();
    }
    dst[i] = csum[c] + sd[t] - v;
}

__global__ void place_pay(const int* __restrict__ keys, const int* __restrict__ payload,
                          int* __restrict__ cursor, int* __restrict__ pay, int n) {
    int i = blockIdx.x * 256 + threadIdx.x;
    if (i < n) {
        int p = atomicAdd(&cursor[keys[i]], 1);
        pay[p] = payload[i];
    }
}

// ---------------- CSR gather, float4-vectorized (f64 reg accumulation -> replay-stable) ----------------
template<bool SELF, bool SCALE, bool DINV>
__global__ void gather_rows4(const float* __restrict__ src,
                             const int* __restrict__ off, const int* __restrict__ pay,
                             const float* __restrict__ self_src,
                             const int* __restrict__ degoff, const float* __restrict__ tbias,
                             float* __restrict__ out, int R, int F4) {
    int i = blockIdx.x * 256 + threadIdx.x;
    if (i >= R * F4) return;
    int r = i / F4, f4 = i - r * F4;
    int b = off[r], e = off[r + 1];
    double a0 = 0.0, a1 = 0.0, a2 = 0.0, a3 = 0.0;
    for (int j = b; j < e; j++) {
        int p = pay[j];
        float4 v = *((const float4*)(src + (size_t)p * F4 * 4) + f4);
        if (DINV) {
            int d = degoff[p + 1] - degoff[p];
            float inv = d > 0 ? 1.f / d : 0.f;
            a0 += (double)(v.x * inv); a1 += (double)(v.y * inv);
            a2 += (double)(v.z * inv); a3 += (double)(v.w * inv);
        } else {
            a0 += v.x; a1 += v.y; a2 += v.z; a3 += v.w;
        }
    }
    float s0 = (float)a0, s1 = (float)a1, s2 = (float)a2, s3 = (float)a3;
    int cnt = e - b;
    if (DINV) {
        float4 bv = *((const float4*)tbias + f4);
        s0 += cnt * bv.x; s1 += cnt * bv.y; s2 += cnt * bv.z; s3 += cnt * bv.w;
    }
    if (SCALE) {
        float inv = 1.f / fmaxf((float)cnt, 1.f);
        s0 *= inv; s1 *= inv; s2 *= inv; s3 *= inv;
    }
    if (SELF) {
        float4 sv = *((const float4*)self_src + i);
        s0 += sv.x; s1 += sv.y; s2 += sv.z; s3 += sv.w;
    }
    float4 o = {s0, s1, s2, s3};
    *((float4*)out + i) = o;
}

// ---------------- small-K GEMM: C[M,N] f32 = act(A[M,K] f32 @ Wbf[N,KP]^T + b) ----------------
template<bool RELU, int KP>
__global__ __launch_bounds__(256) void gemm_smallk(const float* __restrict__ A,
                                                   const unsigned short* __restrict__ Wbf,
                                                   const float* __restrict__ bias,
                                                   float* __restrict__ C,
                                                   int M, int N, int K) {
    __shared__ __align__(16) char Ab[64 * KP * 2];
    const int tid = threadIdx.x;
    const int bm = blockIdx.x * 64;
    const int wid = tid >> 6, lane = tid & 63;
    const int lr = lane & 15, lg = lane >> 4;
    constexpr int NKK = KP / 32;
    constexpr int CHUNKS = 64 * (KP / 4);

    for (int u = tid; u < CHUNKS; u += 256) {
        int row = u / (KP / 4);
        int kq = (u % (KP / 4)) * 4;
        int off = (row * (KP * 2) + kq * 2) ^ ((row & 7) << 4);
        short4_t sv = {0, 0, 0, 0};
        int gm = bm + row;
        if (gm < M && kq + 4 <= K) {
            float4 f = *(const float4*)(A + (size_t)gm * K + kq);
            sv[0] = (short)f2bf(f.x); sv[1] = (short)f2bf(f.y);
            sv[2] = (short)f2bf(f.z); sv[3] = (short)f2bf(f.w);
        }
        *(short4_t*)(Ab + off) = sv;
    }
    __syncthreads();

    bf16x8 af[NKK];
#pragma unroll
    for (int kk = 0; kk < NKK; kk++) {
        int row = wid * 16 + lr;
        af[kk] = *(const bf16x8*)(Ab + ((row * (KP * 2) + kk * 64 + lg * 16) ^ ((row & 7) << 4)));
    }

    for (int n0 = 0; n0 < N; n0 += 16) {
        int wrow = n0 + lr;
        bf16x8 bf[NKK];
#pragma unroll
        for (int kk = 0; kk < NKK; kk++) {
            uint4 raw = {0u, 0u, 0u, 0u};
            if (wrow < N) raw = *(const uint4*)(Wbf + (size_t)wrow * KP + kk * 32 + lg * 8);
            bf[kk] = __builtin_bit_cast(bf16x8, raw);
        }
        f32x4 acc = {0.f, 0.f, 0.f, 0.f};
#pragma unroll
        for (int kk = 0; kk < NKK; kk++)
            acc = __builtin_amdgcn_mfma_f32_16x16x32_bf16(af[kk], bf[kk], acc, 0, 0, 0);
        int col = n0 + lr;
        if (col < N) {
            float bv = bias ? bias[col] : 0.f;
#pragma unroll
            for (int r = 0; r < 4; r++) {
                int row = bm + wid * 16 + lg * 4 + r;
                if (row < M) {
                    float v = acc[r] + bv;
                    if (RELU) v = fmaxf(v, 0.f);
                    C[(size_t)row * N + col] = v;
                }
            }
        }
    }
}

// ---------------- bf16 GEMM 128x128, BK=64, global_load_lds staging; optional grid.z split-K ----------------
template<bool PARTIAL>
__global__ __launch_bounds__(256) void gemm_bf16(const unsigned short* __restrict__ A,
                                                 const unsigned short* __restrict__ B,
                                                 unsigned short* __restrict__ C,
                                                 float* __restrict__ Cp,
                                                 int M, int N, int K, int kchunk) {
    __shared__ __align__(16) char Asm[16384];   // 128 x 64 bf16, swizzled view on read
    __shared__ __align__(16) char Bsm[16384];
    const int tid = threadIdx.x;
    const int nwg = gridDim.x * gridDim.y;
    const int wg = xcd_swizzle(blockIdx.y * gridDim.x + blockIdx.x, nwg);
    const int bm = (wg % gridDim.y) * 128, bn = (wg / gridDim.y) * 128;
    const int wid = tid >> 6, lane = tid & 63;
    const int wm = (wid >> 1) * 64, wn = (wid & 1) * 64;
    const int lr = lane & 15, lg = lane >> 4;
    const int kbeg = blockIdx.z * kchunk;
    const int kend = min(K, kbeg + kchunk);

    f32x4 zero = {0.f, 0.f, 0.f, 0.f};
    f32x4 acc[4][4];
#pragma unroll
    for (int i = 0; i < 4; i++)
#pragma unroll
        for (int j = 0; j < 4; j++) acc[i][j] = zero;

    for (int k0 = kbeg; k0 < kend; k0 += 64) {
#pragma unroll
        for (int u = 0; u < 4; u++) {
            int blk = wid * 4 + u;               // 0..15 (1KB LDS blocks)
            int row = blk * 8 + (lane >> 3);     // 8 rows per block
            int ch  = (lane & 7) ^ (row & 7);    // inverse swizzle on source
            const unsigned short* gA = A + (size_t)(bm + row) * K + k0 + ch * 8;
            __builtin_amdgcn_global_load_lds(
                (const __attribute__((address_space(1))) unsigned int*)gA,
                (__attribute__((address_space(3))) unsigned int*)(Asm + blk * 1024),
                16, 0, 0);
            const unsigned short* gB = B + (size_t)(bn + row) * K + k0 + ch * 8;
            __builtin_amdgcn_global_load_lds(
                (const __attribute__((address_space(1))) unsigned int*)gB,
                (__attribute__((address_space(3))) unsigned int*)(Bsm + blk * 1024),
                16, 0, 0);
        }
        __syncthreads();
#pragma unroll
        for (int kk = 0; kk < 2; kk++) {
            bf16x8 af[4], bf[4];
#pragma unroll
            for (int m = 0; m < 4; m++) {
                int row = wm + m * 16 + lr;
                af[m] = *(const bf16x8*)(Asm + ((row * 128 + kk * 64 + lg * 16) ^ ((row & 7) << 4)));
            }
#pragma unroll
            for (int n = 0; n < 4; n++) {
                int row = wn + n * 16 + lr;
                bf[n] = *(const bf16x8*)(Bsm + ((row * 128 + kk * 64 + lg * 16) ^ ((row & 7) << 4)));
            }
#pragma unroll
            for (int m = 0; m < 4; m++)
#pragma unroll
                for (int n = 0; n < 4; n++)
                    acc[m][n] = __builtin_amdgcn_mfma_f32_16x16x32_bf16(af[m], bf[n], acc[m][n], 0, 0, 0);
        }
        __syncthreads();
    }
#pragma unroll
    for (int m = 0; m < 4; m++)
#pragma unroll
        for (int n = 0; n < 4; n++) {
            int col = bn + wn + n * 16 + lr;
#pragma unroll
            for (int r = 0; r < 4; r++) {
                int row = bm + wm + m * 16 + lg * 4 + r;
                if (PARTIAL)
                    Cp[(size_t)blockIdx.z * M * N + (size_t)row * N + col] = acc[m][n][r];
                else
                    C[(size_t)row * N + col] = f2bf(acc[m][n][r]);
            }
        }
}

// ---------------- MFMA GEMM 64x64, wave-K-split, reg-prefetch, 32KB LDS, grid.z split-K ----------------
template<bool RELU, bool PARTIAL, typename TA, typename TW>
__global__ __launch_bounds__(256) void gemm64(const TA* __restrict__ A,
                                              const TW* __restrict__ W,
                                              const float* __restrict__ bias,
                                              float* __restrict__ C,
                                              int M, int N, int K, int kchunk) {
    __shared__ __align__(16) char pool[32768];
    char* Ab = pool;
    char* Bb = pool + 16384;
    const int tid = threadIdx.x;
    const int nwg = gridDim.x * gridDim.y;
    const int wg = xcd_swizzle(blockIdx.y * gridDim.x + blockIdx.x, nwg);
    const int bm = (wg / gridDim.x) * 64, bn = (wg % gridDim.x) * 64;
    const int wid = tid >> 6, lane = tid & 63;
    const int lr = lane & 15, lg = lane >> 4;
    const int kbeg = blockIdx.z * kchunk;
    const int kend = min(K, kbeg + kchunk);
    const bool kvec = ((K & 3) == 0);

    f32x4 zero = {0.f, 0.f, 0.f, 0.f};
    f32x4 acc[4][4];
#pragma unroll
    for (int i = 0; i < 4; i++)
#pragma unroll
        for (int j = 0; j < 4; j++) acc[i][j] = zero;

    uint4 ra16[4], rb16[4];
    short4_t ra4[8], rb4[8];

    auto load_A = [&](int kc2) {
        if constexpr (sizeof(TA) == 2) {
#pragma unroll
            for (int u = 0; u < 4; u++) {
                int s = u * 256 + tid;
                int row = s >> 4, k8 = (s & 15) << 3;
                int gk = kc2 + k8, gm = bm + row;
                uint4 v = {0u, 0u, 0u, 0u};
                if (gm < M && gk + 8 <= kend) {
                    v = *(const uint4*)((const unsigned short*)A + (size_t)gm * K + gk);
                } else if (gm < M && gk < kend) {
                    unsigned short tmp[8];
#pragma unroll
                    for (int e = 0; e < 8; e++)
                        tmp[e] = (gk + e < kend) ? ((const unsigned short*)A)[(size_t)gm * K + gk + e] : 0;
                    v = *(const uint4*)tmp;
                }
                ra16[u] = v;
            }
        } else {
#pragma unroll
            for (int u = 0; u < 8; u++) {
                int s = u * 256 + tid;
                int row = s >> 5, kq = (s & 31) << 2;
                int gk = kc2 + kq, gm = bm + row;
                short4_t sv = {0, 0, 0, 0};
                if (gm < M && gk < kend)
                    sv = ld4bf_f32((const float*)A + (size_t)gm * K + gk, gk, kend, kvec);
                ra4[u] = sv;
            }
        }
    };
    auto load_B = [&](int kc2) {
        if constexpr (sizeof(TW) == 2) {
#pragma unroll
            for (int u = 0; u < 4; u++) {
                int s = u * 256 + tid;
                int row = s >> 4, k8 = (s & 15) << 3;
                int gk = kc2 + k8, gn = bn + row;
                uint4 v = {0u, 0u, 0u, 0u};
                if (gn < N && gk + 8 <= kend) {
                    v = *(const uint4*)((const unsigned short*)W + (size_t)gn * K + gk);
                } else if (gn < N && gk < kend) {
                    unsigned short tmp[8];
#pragma unroll
                    for (int e = 0; e < 8; e++)
                        tmp[e] = (gk + e < kend) ? ((const unsigned short*)W)[(size_t)gn * K + gk + e] : 0;
                    v = *(const uint4*)tmp;
                }
                rb16[u] = v;
            }
        } else {
#pragma unroll
            for (int u = 0; u < 8; u++) {
                int s = u * 256 + tid;
                int row = s >> 5, kq = (s & 31) << 2;
                int gk = kc2 + kq, gn = bn + row;
                short4_t sv = {0, 0, 0, 0};
                if (gn < N && gk < kend)
                    sv = ld4bf_f32((const float*)W + (size_t)gn * K + gk, gk, kend, kvec);
                rb4[u] = sv;
            }
        }
    };
    auto write_A = [&]() {
        if constexpr (sizeof(TA) == 2) {
#pragma unroll
            for (int u = 0; u < 4; u++) {
                int s = u * 256 + tid;
                int row = s >> 4, k8 = (s & 15) << 3;
                int off = (row * 256 + k8 * 2) ^ ((row & 7) << 4);
                *(uint4*)(Ab + off) = ra16[u];
            }
        } else {
#pragma unroll
            for (int u = 0; u < 8; u++) {
                int s = u * 256 + tid;
                int row = s >> 5, kq = (s & 31) << 2;
                int off = (row * 256 + kq * 2) ^ ((row & 7) << 4);
                *(short4_t*)(Ab + off) = ra4[u];
            }
        }
    };
    auto write_B = [&]() {
        if constexpr (sizeof(TW) == 2) {
#pragma unroll
            for (int u = 0; u < 4; u++) {
                int s = u * 256 + tid;
                int row = s >> 4, k8 = (s & 15) << 3;
                int off = (row * 256 + k8 * 2) ^ ((row & 7) << 4);
                *(uint4*)(Bb + off) = rb16[u];
            }
        } else {
#pragma unroll
            for (int u = 0; u < 8; u++) {
                int s = u * 256 + tid;
                int row = s >> 5, kq = (s & 31) << 2;
                int off = (row * 256 + kq * 2) ^ ((row & 7) << 4);
                *(short4_t*)(Bb + off) = rb4[u];
            }
        }
    };

    load_A(kbeg);
    load_B(kbeg);
    for (int kc = kbeg; kc < kend; kc += 128) {
        write_A();
        write_B();
        __syncthreads();
        if (kc + 128 < kend) { load_A(kc + 128); load_B(kc + 128); }

        bf16x8 af[4], bf[4];
        const int kb = wid * 64 + lg * 16;
#pragma unroll
        for (int m = 0; m < 4; m++) {
            int row = m * 16 + lr;
            af[m] = *(const bf16x8*)(Ab + ((row * 256 + kb) ^ ((row & 7) << 4)));
        }
#pragma unroll
        for (int n = 0; n < 4; n++) {
            int row = n * 16 + lr;
            bf[n] = *(const bf16x8*)(Bb + ((row * 256 + kb) ^ ((row & 7) << 4)));
        }
#pragma unroll
        for (int m = 0; m < 4; m++)
#pragma unroll
            for (int n = 0; n < 4; n++)
                acc[m][n] = __builtin_amdgcn_mfma_f32_16x16x32_bf16(af[m], bf[n], acc[m][n], 0, 0, 0);
        __syncthreads();
    }

    float* redA = (float*)pool;
    float* redB = (float*)(pool + 16384);
    if (wid < 2) {
        float* r = (wid == 0) ? redA : redB;
#pragma unroll
        for (int m = 0; m < 4; m++)
#pragma unroll
            for (int n = 0; n < 4; n++)
#pragma unroll
                for (int r4 = 0; r4 < 4; r4++)
                    r[(m * 16 + lg * 4 + r4) * 64 + n * 16 + lr] = acc[m][n][r4];
    }
    __syncthreads();
    if (wid >= 2) {
        float* r = (wid == 2) ? redA : redB;
#pragma unroll
        for (int m = 0; m < 4; m++)
#pragma unroll
            for (int n = 0; n < 4; n++)
#pragma unroll
                for (int r4 = 0; r4 < 4; r4++)
                    r[(m * 16 + lg * 4 + r4) * 64 + n * 16 + lr] += acc[m][n][r4];
    }
    __syncthreads();
#pragma unroll
    for (int u = 0; u < 16; u++) {
        int idx = u * 256 + tid;
        int row = idx >> 6, col = idx & 63;
        int gm = bm + row, gn = bn + col;
        if (gm >= M || gn >= N) continue;
        float s = redA[idx] + redB[idx];
        if (PARTIAL) {
            C[(size_t)blockIdx.z * M * N + (size_t)gm * N + gn] = s;
        } else {
            s += bias ? bias[gn] : 0.f;
            if (RELU) s = fmaxf(s, 0.f);
            C[(size_t)gm * N + gn] = s;
        }
    }
}

template<bool RELU>
__global__ void reduce_partial(const float* __restrict__ part, const float* __restrict__ bias,
                               float* __restrict__ C, int MN, int N, int SK) {
    int i = blockIdx.x * 256 + threadIdx.x;
    if (i >= MN) return;
    float s = 0.f;
    for (int z = 0; z < SK; z++) s += part[(size_t)z * MN + i];
    s += bias ? bias[i % N] : 0.f;
    if (RELU) s = fmaxf(s, 0.f);
    C[i] = s;
}

// reduce + bias (+relu), output either f32 or bf16
template<bool RELU, bool OUTBF>
__global__ void reduce_partial2(const float* __restrict__ part, const float* __restrict__ bias,
                                void* __restrict__ Cv, int MN, int N, int SK) {
    int i = blockIdx.x * 256 + threadIdx.x;
    if (i >= MN) return;
    float s = 0.f;
    for (int z = 0; z < SK; z++) s += part[(size_t)z * MN + i];
    s += bias ? bias[i % N] : 0.f;
    if (RELU) s = fmaxf(s, 0.f);
    if (OUTBF) ((unsigned short*)Cv)[i] = f2bf(s);
    else       ((float*)Cv)[i] = s;
}

// ---------------- cvt W [Nw][K] f32 -> [Nw][Kp] bf16 (zero-padded K) ----------------
__global__ void cvt_w_pad(const float* __restrict__ W, unsigned short* __restrict__ Wb,
                          int Nw, int K, int Kp) {
    int i = blockIdx.x * 256 + threadIdx.x;
    if (i >= Nw * Kp) return;
    int r = i / Kp, k = i - r * Kp;
    Wb[i] = (k < K) ? f2bf(W[(size_t)r * K + k]) : (unsigned short)0;
}

// ---------------- fused GIN2 GEMM + bias + relu + 50-row max/mean pool -> bf16 [1024][1792] ----------------
__global__ __launch_bounds__(256) void gin2pool(const float* __restrict__ xin2,
                                                const unsigned short* __restrict__ Wbf,
                                                const float* __restrict__ bias,
                                                unsigned short* __restrict__ out) {
    __shared__ __align__(16) char Ab[16384];
    const int tid = threadIdx.x;
    const int g = blockIdx.x;
    const int wid = tid >> 6, lane = tid & 63;
    const int lr = lane & 15, lg = lane >> 4;
    const int K = FXD;
    const int N = 840;

#pragma unroll
    for (int u = 0; u < 8; u++) {
        int s = u * 256 + tid;
        int row = s >> 5, kq = (s & 31) << 2;
        int off = (row * 256 + (s & 31) * 8) ^ ((row & 7) << 4);
        float v0 = 0.f, v1 = 0.f, v2 = 0.f, v3 = 0.f;
        if (row < NPG && kq < K) {
            float4 f = *(const float4*)(xin2 + ((size_t)g * NPG + row) * K + kq);
            v0 = f.x; v1 = f.y; v2 = f.z; v3 = f.w;
        }
        short4_t sv;
        sv[0] = (short)f2bf(v0); sv[1] = (short)f2bf(v1);
        sv[2] = (short)f2bf(v2); sv[3] = (short)f2bf(v3);
        *(short4_t*)(Ab + off) = sv;
    }
    __syncthreads();

    bf16x8 af[4][3];
#pragma unroll
    for (int m = 0; m < 4; m++)
#pragma unroll
        for (int kk = 0; kk < 3; kk++) {
            int row = m * 16 + lr;
            af[m][kk] = *(const bf16x8*)(Ab + ((row * 256 + kk * 64 + lg * 16) ^ ((row & 7) << 4)));
        }

    for (int t = 0; t < 14; t++) {
        const int n0 = t * 64 + wid * 16;
        const int wrow = n0 + lr;
        bf16x8 bf[3];
#pragma unroll
        for (int kk = 0; kk < 3; kk++) {
            int k0 = kk * 32 + lg * 8;
            uint4 raw = {0u, 0u, 0u, 0u};
            if (wrow < N) raw = *(const uint4*)(Wbf + (size_t)wrow * 96 + k0);
            bf[kk] = __builtin_bit_cast(bf16x8, raw);
        }
        f32x4 zero = {0.f, 0.f, 0.f, 0.f};
        f32x4 acc[4] = {zero, zero, zero, zero};
#pragma unroll
        for (int m = 0; m < 4; m++)
#pragma unroll
            for (int kk = 0; kk < 3; kk++)
                acc[m] = __builtin_amdgcn_mfma_f32_16x16x32_bf16(af[m][kk], bf[kk], acc[m], 0, 0, 0);

        const int c = n0 + lr;
        float bv = (c < N) ? bias[c] : 0.f;
        float mx = -1e30f, sm = 0.f;
#pragma unroll
        for (int m = 0; m < 4; m++)
#pragma unroll
            for (int r = 0; r < 4; r++) {
                int row = m * 16 + lg * 4 + r;
                if (row < NPG) {
                    float v = fmaxf(acc[m][r] + bv, 0.f);
                    mx = fmaxf(mx, v);
                    sm += v;
                }
            }
        mx = fmaxf(mx, __shfl_xor(mx, 16, 64));
        sm += __shfl_xor(sm, 16, 64);
        mx = fmaxf(mx, __shfl_xor(mx, 32, 64));
        sm += __shfl_xor(sm, 32, 64);
        if (lg == 0 && c < N) {
            out[(size_t)g * 1792 + c] = f2bf(mx);
            out[(size_t)g * 1792 + 840 + c] = f2bf(sm * (1.f / NPG));
        }
    }
    if (tid < 112) out[(size_t)g * 1792 + 1680 + tid] = 0;
}

// ---------------- N=1 GEMM ----------------
__global__ __launch_bounds__(256) void rowdot(const float* __restrict__ A,
                                              const float* __restrict__ w,
                                              const float* __restrict__ b,
                                              float* __restrict__ out, int Mrows, int K) {
    int row = blockIdx.x * 4 + (threadIdx.x >> 6);
    int lane = threadIdx.x & 63;
    if (row >= Mrows) return;
    float s = 0.f;
    for (int k = lane; k < K; k += 64) s += A[(size_t)row * K + k] * w[k];
#pragma unroll
    for (int off = 32; off > 0; off >>= 1) s += __shfl_xor(s, off, 64);
    if (lane == 0) out[row] = s + b[0];
}

// ---------------- fused node-gather + Dinv + bias + pool, ONE BLOCK PER GRAPH ----------------
// 256 threads = 4 node-segments x 64 float4-cols; ~12 nodes/thread; LDS combine.
__global__ __launch_bounds__(256) void pool_hyper_fused(const float* __restrict__ e2,
                                                        const int* __restrict__ off_n,
                                                        const int* __restrict__ pay_n,
                                                        const float* __restrict__ b,
                                                        unsigned short* __restrict__ out) {
    __shared__ float smx[4][256];
    __shared__ float ssm[4][256];
    const int tid = threadIdx.x;
    const int g = blockIdx.x;
    const int o4 = tid & 63, seg = tid >> 6;
    const int r0 = seg * 13, r1 = (seg < 3) ? r0 + 13 : NPG;   // 13,13,13,11
    float4 bv = *((const float4*)b + o4);
    float mx0 = -1e30f, mx1 = -1e30f, mx2 = -1e30f, mx3 = -1e30f;
    float sm0 = 0.f, sm1 = 0.f, sm2 = 0.f, sm3 = 0.f;
    for (int n = r0; n < r1; n++) {
        int node = g * NPG + n;
        int bb = off_n[node], ee = off_n[node + 1];
        double a0 = 0.0, a1 = 0.0, a2 = 0.0, a3 = 0.0;
        for (int j = bb; j < ee; j++) {
            float4 v = *((const float4*)(e2 + (size_t)pay_n[j] * 256) + o4);
            a0 += v.x; a1 += v.y; a2 += v.z; a3 += v.w;
        }
        int d = ee - bb;
        float inv = d > 0 ? 1.f / d : 0.f;
        float v0 = (float)a0 * inv + bv.x;
        float v1 = (float)a1 * inv + bv.y;
        float v2 = (float)a2 * inv + bv.z;
        float v3 = (float)a3 * inv + bv.w;
        mx0 = fmaxf(mx0, v0); sm0 += v0;
        mx1 = fmaxf(mx1, v1); sm1 += v1;
        mx2 = fmaxf(mx2, v2); sm2 += v2;
        mx3 = fmaxf(mx3, v3); sm3 += v3;
    }
    smx[seg][o4 * 4 + 0] = mx0; smx[seg][o4 * 4 + 1] = mx1;
    smx[seg][o4 * 4 + 2] = mx2; smx[seg][o4 * 4 + 3] = mx3;
    ssm[seg][o4 * 4 + 0] = sm0; ssm[seg][o4 * 4 + 1] = sm1;
    ssm[seg][o4 * 4 + 2] = sm2; ssm[seg][o4 * 4 + 3] = sm3;
    __syncthreads();
    if (tid < 256 && seg == 0) {
        // threads 0..63 combine all 4 segments for their o4 (4 elems each)
#pragma unroll
        for (int e = 0; e < 4; e++) {
            int idx = o4 * 4 + e;
            float m = fmaxf(fmaxf(smx[0][idx], smx[1][idx]), fmaxf(smx[2][idx], smx[3][idx]));
            float s = ssm[0][idx] + ssm[1][idx] + ssm[2][idx] + ssm[3][idx];
            out[(size_t)g * 512 + idx] = f2bf(m);
            out[(size_t)g * 512 + 256 + idx] = f2bf(s * (1.f / NPG));
        }
    }
}

// ---------------- pack fusion tokens -> bf16 ----------------
__global__ void pack_tokens_bf(const float* __restrict__ fp_o, const float* __restrict__ xg,
                               const float* __restrict__ hxg, const float* __restrict__ t,
                               unsigned short* __restrict__ in_t) {
    int i = blockIdx.x * 256 + threadIdx.x;
    if (i >= 4096 * 512) return;
    int d = i & 511;
    int row = i >> 9;
    int tok = row & 3, b = row >> 2;
    const float* s = (tok == 0) ? fp_o : (tok == 1) ? xg : (tok == 2) ? hxg : t;
    in_t[i] = f2bf(s[b * 512 + d]);
}

// ---------------- concat + cvt Wq|Wk|Wv -> bf16 [6144][512] ----------------
__global__ void cvt_qkv_w(const float* __restrict__ Wq, const float* __restrict__ Wk,
                          const float* __restrict__ Wv, unsigned short* __restrict__ Wb) {
    int i = blockIdx.x * 256 + threadIdx.x;
    if (i >= 6144 * 512) return;
    int n = i >> 9;
    const float* src = (n < 2048) ? Wq : (n < 4096) ? Wk : Wv;
    int nn = (n < 2048) ? n : (n < 4096) ? n - 2048 : n - 4096;
    Wb[i] = f2bf(src[(size_t)nn * 512 + (i & 511)]);
}

// ---------------- fused attention + conv3x3 + relu -> cbuf bf16 [1024][4096] ----------------
__global__ __launch_bounds__(256) void attn_conv(const unsigned short* __restrict__ QKV,
                                                 const float* __restrict__ cw,
                                                 const float* __restrict__ cb,
                                                 unsigned short* __restrict__ c) {
    __shared__ float att_s[4][4][512];   // [head][token][d] = 32 KB
    __shared__ float w[144];
    __shared__ float bias[4];
    const int tid = threadIdx.x;
    const int wid = tid >> 6, lane = tid & 63;
    const int b = blockIdx.x;
    if (tid < 144) w[tid] = cw[tid];
    if (tid < 4) bias[tid] = cb[tid];

    const unsigned short* qb = QKV + (size_t)b * 4 * 6144 + wid * 512;
    const unsigned short* kb = qb + 2048;
    const unsigned short* vb = qb + 4096;
    float qr[4][8], kr[4][8];
#pragma unroll
    for (int n = 0; n < 4; n++)
#pragma unroll
        for (int cc = 0; cc < 8; cc++) {
            qr[n][cc] = bf2f(qb[n * 6144 + cc * 64 + lane]);
            kr[n][cc] = bf2f(kb[n * 6144 + cc * 64 + lane]);
        }
    float s[4][4];
#pragma unroll
    for (int n = 0; n < 4; n++)
#pragma unroll
        for (int m = 0; m < 4; m++) {
            float p = 0.f;
#pragma unroll
            for (int cc = 0; cc < 8; cc++) p += qr[n][cc] * kr[m][cc];
#pragma unroll
            for (int off = 32; off > 0; off >>= 1) p += __shfl_xor(p, off, 64);
            s[n][m] = p * 0.04419417382415922f;   // 1/sqrt(512)
        }
    float pm[4][4];
#pragma unroll
    for (int n = 0; n < 4; n++) {
        float mx = fmaxf(fmaxf(s[n][0], s[n][1]), fmaxf(s[n][2], s[n][3]));
        float e0 = expf(s[n][0] - mx), e1 = expf(s[n][1] - mx);
        float e2 = expf(s[n][2] - mx), e3 = expf(s[n][3] - mx);
        float inv = 1.f / (e0 + e1 + e2 + e3);
        pm[n][0] = e0 * inv; pm[n][1] = e1 * inv; pm[n][2] = e2 * inv; pm[n][3] = e3 * inv;
    }
#pragma unroll
    for (int cc = 0; cc < 8; cc++) {
        float v0 = bf2f(vb[0 * 6144 + cc * 64 + lane]);
        float v1 = bf2f(vb[1 * 6144 + cc * 64 + lane]);
        float v2 = bf2f(vb[2 * 6144 + cc * 64 + lane]);
        float v3 = bf2f(vb[3 * 6144 + cc * 64 + lane]);
#pragma unroll
        for (int n = 0; n < 4; n++)
            att_s[wid][n][cc * 64 + lane] = pm[n][0] * v0 + pm[n][1] * v1 + pm[n][2] * v2 + pm[n][3] * v3;
    }
    __syncthreads();

    for (int it = 0; it < 16; it++) {
        int j = it * 256 + tid;            // 0..4095
        float v = 0.f;
        if (j < 4080) {
            int wo = j % 510;
            int r = j / 510;
            int ho = r & 1, co = r >> 1;
            float acc = bias[co];
#pragma unroll
            for (int ci = 0; ci < 4; ci++)
#pragma unroll
                for (int kh = 0; kh < 3; kh++)
#pragma unroll
                    for (int kw = 0; kw < 3; kw++)
                        acc += att_s[ci][ho + kh][wo + kw] * w[((co * 4 + ci) * 3 + kh) * 3 + kw];
            v = fmaxf(acc, 0.f);
        }
        c[(size_t)b * 4096 + j] = f2bf(v);
    }
}

// ---------------- host side ----------------
template<typename TA, typename TW>
static inline void launch_gemm64(const TA* A, const TW* W, const float* b, float* C,
                                 int M, int N, int K, bool relu, float* part, hipStream_t s) {
    int gx = (N + 63) / 64, gy = (M + 63) / 64;
    int targetSK = 1024 / (gx * gy);
    if (targetSK < 1) targetSK = 1;
    if (targetSK > 8) targetSK = 8;
    int kchunk = K, SK = 1;
    if (targetSK > 1) {
        kchunk = (((K + targetSK - 1) / targetSK) + 127) & ~127;
        SK = (K + kchunk - 1) / kchunk;
    }
    if (SK <= 1) {
        dim3 g(gx, gy);
        if (relu) gemm64<true, false, TA, TW><<<g, 256, 0, s>>>(A, W, b, C, M, N, K, K);
        else      gemm64<false, false, TA, TW><<<g, 256, 0, s>>>(A, W, b, C, M, N, K, K);
    } else {
        dim3 g(gx, gy, SK);
        gemm64<false, true, TA, TW><<<g, 256, 0, s>>>(A, W, nullptr, part, M, N, K, kchunk);
        int MN = M * N;
        if (relu) reduce_partial<true><<<(MN + 255) / 256, 256, 0, s>>>(part, b, C, MN, N, SK);
        else      reduce_partial<false><<<(MN + 255) / 256, 256, 0, s>>>(part, b, C, MN, N, SK);
    }
}

extern "C" void kernel_launch(void* const* d_in, const int* in_sizes, int n_in,
                              void* d_out, int out_size, void* d_ws, size_t ws_size,
                              hipStream_t stream) {
    const float* x       = (const float*)d_in[0];
    const int*   edge    = (const int*)d_in[1];
    const int*   hedge   = (const int*)d_in[3];
    const float* fp      = (const float*)d_in[4];
    const float* text_em = (const float*)d_in[5];
    const float* fc1_W = (const float*)d_in[7];  const float* fc1_b = (const float*)d_in[8];
    const float* fc2_W = (const float*)d_in[9];  const float* fc2_b = (const float*)d_in[10];
    const float* fc3_W = (const float*)d_in[11]; const float* fc3_b = (const float*)d_in[12];
    const float* fcg1_W = (const float*)d_in[13]; const float* fcg1_b = (const float*)d_in[14];
    const float* fcg2_W = (const float*)d_in[15]; const float* fcg2_b = (const float*)d_in[16];
    const float* fchg1_W = (const float*)d_in[17]; const float* fchg1_b = (const float*)d_in[18];
    const float* fchg2_W = (const float*)d_in[19]; const float* fchg2_b = (const float*)d_in[20];
    const float* gin1_W = (const float*)d_in[21]; const float* gin1_b = (const float*)d_in[22];
    const float* gin2_W = (const float*)d_in[23]; const float* gin2_b = (const float*)d_in[24];
    const float* h3_W = (const float*)d_in[25]; const float* h3_b = (const float*)d_in[26];
    const float* h4_W = (const float*)d_in[27]; const float* h4_b = (const float*)d_in[28];
    const float* Wq = (const float*)d_in[29];
    const float* Wk = (const float*)d_in[30];
    const float* Wv = (const float*)d_in[31];
    const float* conv_W = (const float*)d_in[32]; const float* conv_b = (const float*)d_in[33];
    const float* mlp1_W = (const float*)d_in[34]; const float* mlp1_b = (const float*)d_in[35];
    const float* mlp2_W = (const float*)d_in[36]; const float* mlp2_b = (const float*)d_in[37];

    const int* e_src = edge;
    const int* e_dst = edge + N_EDGES;
    const int* h_nid = hedge;
    const int* h_eid = hedge + N_HNNZ;

    float* ws = (float*)d_ws;
    const size_t ZONE = 51609600;
    // ---- phase A (GIN) ----
    float* xin1 = ws;                               // 4,300,800
    float* xg1  = ws + 4300800;                     // 4,300,800
    float* xin2 = ws + 8601600;                     // 4,300,800
    // ---- phase H (hypergraph) ----
    float* eagg   = ws;                             // 860,160
    float* e1_32  = ws + 860160;                    // 1,720,320
    float* hnode  = ws + 2580480;                   // 8,601,600
    float* eagg2  = ws + 19783680;                  // 1,720,320
    float* e2_32  = ws + 21504000;                  // 2,621,440 (ends 24,125,440)
    // ---- phase D (attention) ----
    unsigned short* in_t_bf  = (unsigned short*)ws;                 // 2,097,152 us
    unsigned short* qkv_bf   = (unsigned short*)(ws + 2097152);     // 25,165,824 us
    unsigned short* cbuf_bf  = (unsigned short*)(ws + 35651584);    // 4,194,304 us (1024x4096)
    float* m1   = ws + 39829504;                                    // 1,048,576
    unsigned short* Wqkv_bf  = (unsigned short*)(ws + 40878080);    // 3,145,728 us
    unsigned short* mlp1W_bf = (unsigned short*)(ws + 42450944);    // 4,194,304 us (ends 44,548,096)
    float* part = ws;                               // split-K partial scratch (zone-dead windows)
    // ---- CSR + weight-cvt region (above phase high-water marks, inside ZONE) ----
    int* cnt_g = (int*)(ws + 45000000);
    int* off_g = (int*)(ws + 45051200);
    int* pay_g = (int*)(ws + 45102401);
    int* cnt_e = (int*)(ws + 45307201);
    int* off_e = (int*)(ws + 45317441);
    int* pay_e = (int*)(ws + 45327682);
    int* cnt_n = (int*)(ws + 45430082);
    int* off_n = (int*)(ws + 45481282);
    int* pay_n = (int*)(ws + 45532483);             // ends 45,634,883
    int* csum  = (int*)(ws + 45650000);             // 440 ints
    unsigned short* gin2Wbf  = (unsigned short*)(ws + 45700000);    // 80,640 us
    unsigned short* fcg1Wbf  = (unsigned short*)(ws + 45800000);    // 1,835,008 us
    unsigned short* fcg2Wbf  = (unsigned short*)(ws + 46750000);    // 524,288 us
    unsigned short* fchg1Wbf = (unsigned short*)(ws + 47050000);    // 524,288 us
    unsigned short* fchg2Wbf = (unsigned short*)(ws + 47350000);    // 524,288 us
    unsigned short* gin1Wbf  = (unsigned short*)(ws + 47700000);    // 84x96 us
    unsigned short* h3Wbf    = (unsigned short*)(ws + 47750000);    // 168x96 us
    unsigned short* h4Wbf    = (unsigned short*)(ws + 47800000);    // 256x192 us
    unsigned short* fp_bf    = (unsigned short*)(ws + 48000000);    // 1024x2560 us
    unsigned short* text_bf  = (unsigned short*)(ws + 49350000);    // 1024x768 us
    unsigned short* fc1Wbf   = (unsigned short*)(ws + 49800000);    // 128x2560 us
    unsigned short* fc3Wbf   = (unsigned short*)(ws + 50000000);    // 512x768 us (ends < ZONE)
    // ---- persistent ----
    unsigned short* xg_raw_bf = (unsigned short*)(ws + ZONE);           // 1024x1792 us
    unsigned short* xg_mid_bf = (unsigned short*)(ws + ZONE + 1720320); // 1024x1024 us
    unsigned short* hx_raw_bf = (unsigned short*)(ws + ZONE + 2768896); // 1024x512 us
    unsigned short* hx_mid_bf = (unsigned short*)(ws + ZONE + 3293184); // 1024x1024 us
    float* h1     = ws + ZONE + 4341760;
    float* fp_o   = ws + ZONE + 4472832;
    float* tt     = ws + ZONE + 4997120;
    const size_t NEED = (ZONE + 5582848) * sizeof(float);
    if (ws_size < NEED) return;

    float* out_y  = (float*)d_out;
    float* xg_out = out_y + 1024;
    float* hx_out = out_y + 1024 + 1024 * 512;

    // ---------- build 3 CSR structures (parallel scan) + weight/input converts ----------
    hipMemsetAsync(cnt_g, 0, N_NODES * 4, stream);
    hipMemsetAsync(cnt_e, 0, N_HEDGES * 4, stream);
    hipMemsetAsync(cnt_n, 0, N_NODES * 4, stream);
    histo_i<<<(N_EDGES + 255) / 256, 256, 0, stream>>>(e_dst, cnt_g, N_EDGES);
    histo_i<<<(N_HNNZ + 255) / 256, 256, 0, stream>>>(h_eid, cnt_e, N_HNNZ);
    histo_i<<<(N_HNNZ + 255) / 256, 256, 0, stream>>>(h_nid, cnt_n, N_HNNZ);
    scan1_chunksum<<<440, 256, 0, stream>>>(cnt_g, cnt_e, cnt_n, csum);
    scan2_chunkbase<<<3, 256, 0, stream>>>(csum, off_g, off_e, off_n);
    scan3_writeoff<<<440, 256, 0, stream>>>(cnt_g, cnt_e, cnt_n, csum, off_g, off_e, off_n);
    hipMemcpyAsync(cnt_g, off_g, N_NODES * 4, hipMemcpyDeviceToDevice, stream);
    hipMemcpyAsync(cnt_e, off_e, N_HEDGES * 4, hipMemcpyDeviceToDevice, stream);
    hipMemcpyAsync(cnt_n, off_n, N_NODES * 4, hipMemcpyDeviceToDevice, stream);
    place_pay<<<(N_EDGES + 255) / 256, 256, 0, stream>>>(e_dst, e_src, cnt_g, pay_g, N_EDGES);
    place_pay<<<(N_HNNZ + 255) / 256, 256, 0, stream>>>(h_eid, h_nid, cnt_e, pay_e, N_HNNZ);
    place_pay<<<(N_HNNZ + 255) / 256, 256, 0, stream>>>(h_nid, h_eid, cnt_n, pay_n, N_HNNZ);
    cvt_w_pad<<<(840 * 96 + 255) / 256, 256, 0, stream>>>(gin2_W, gin2Wbf, 840, 84, 96);
    cvt_w_pad<<<(1024 * 1792 + 255) / 256, 256, 0, stream>>>(fcg1_W, fcg1Wbf, 1024, 1680, 1792);
    cvt_w_pad<<<(512 * 1024 + 255) / 256, 256, 0, stream>>>(fcg2_W, fcg2Wbf, 512, 1024, 1024);
    cvt_w_pad<<<(1024 * 512 + 255) / 256, 256, 0, stream>>>(fchg1_W, fchg1Wbf, 1024, 512, 512);
    cvt_w_pad<<<(512 * 1024 + 255) / 256, 256, 0, stream>>>(fchg2_W, fchg2Wbf, 512, 1024, 1024);
    cvt_w_pad<<<(84 * 96 + 255) / 256, 256, 0, stream>>>(gin1_W, gin1Wbf, 84, 84, 96);
    cvt_w_pad<<<(168 * 96 + 255) / 256, 256, 0, stream>>>(h3_W, h3Wbf, 168, 84, 96);
    cvt_w_pad<<<(256 * 192 + 255) / 256, 256, 0, stream>>>(h4_W, h4Wbf, 256, 168, 192);
    cvt_w_pad<<<(1024 * 2560 + 255) / 256, 256, 0, stream>>>(fp, fp_bf, 1024, 2513, 2560);
    cvt_w_pad<<<(128 * 2560 + 255) / 256, 256, 0, stream>>>(fc1_W, fc1Wbf, 128, 2513, 2560);
    cvt_w_pad<<<(1024 * 768 + 255) / 256, 256, 0, stream>>>(text_em, text_bf, 1024, 768, 768);
    cvt_w_pad<<<(512 * 768 + 255) / 256, 256, 0, stream>>>(fc3_W, fc3Wbf, 512, 768, 768);

    // ---------- GIN branch ----------
    gather_rows4<true, false, false><<<(N_NODES * (FXD / 4) + 255) / 256, 256, 0, stream>>>(
        x, off_g, pay_g, x, nullptr, nullptr, xin1, N_NODES, FXD / 4);
    gemm_smallk<true, 96><<<N_NODES / 64, 256, 0, stream>>>(xin1, gin1Wbf, gin1_b, xg1, N_NODES, FXD, FXD);
    gather_rows4<true, false, false><<<(N_NODES * (FXD / 4) + 255) / 256, 256, 0, stream>>>(
        xg1, off_g, pay_g, xg1, nullptr, nullptr, xin2, N_NODES, FXD / 4);
    gin2pool<<<NB, 256, 0, stream>>>(xin2, gin2Wbf, gin2_b, xg_raw_bf);
    gemm_bf16<true><<<dim3(8, 8, 7), 256, 0, stream>>>(
        xg_raw_bf, fcg1Wbf, nullptr, part, 1024, 1024, 1792, 256);
    reduce_partial2<true, true><<<(1024 * 1024 + 255) / 256, 256, 0, stream>>>(
        part, fcg1_b, xg_mid_bf, 1024 * 1024, 1024, 7);
    gemm_bf16<true><<<dim3(4, 8, 8), 256, 0, stream>>>(
        xg_mid_bf, fcg2Wbf, nullptr, part, 1024, 512, 1024, 128);
    reduce_partial2<false, false><<<(1024 * 512 + 255) / 256, 256, 0, stream>>>(
        part, fcg2_b, xg_out, 1024 * 512, 512, 8);

    // ---------- hypergraph branch ----------
    gather_rows4<false, true, false><<<(N_HEDGES * (FXD / 4) + 255) / 256, 256, 0, stream>>>(
        x, off_e, pay_e, nullptr, nullptr, nullptr, eagg, N_HEDGES, FXD / 4);
    gemm_smallk<false, 96><<<N_HEDGES / 64, 256, 0, stream>>>(eagg, h3Wbf, nullptr, e1_32, N_HEDGES, 168, FXD);
    gather_rows4<false, false, false><<<(N_NODES * 42 + 255) / 256, 256, 0, stream>>>(
        e1_32, off_n, pay_n, nullptr, nullptr, nullptr, hnode, N_NODES, 42);
    gather_rows4<false, true, true><<<(N_HEDGES * 42 + 255) / 256, 256, 0, stream>>>(
        hnode, off_e, pay_e, nullptr, off_n, h3_b, eagg2, N_HEDGES, 42);
    gemm_smallk<false, 192><<<N_HEDGES / 64, 256, 0, stream>>>(eagg2, h4Wbf, nullptr, e2_32, N_HEDGES, 256, 168);
    // fused node-gather + Dinv + bias + pool: 1 block/graph, 4 node-segs x 64 cols
    pool_hyper_fused<<<NB, 256, 0, stream>>>(e2_32, off_n, pay_n, h4_b, hx_raw_bf);
    gemm_bf16<true><<<dim3(8, 8, 4), 256, 0, stream>>>(
        hx_raw_bf, fchg1Wbf, nullptr, part, 1024, 1024, 512, 128);
    reduce_partial2<true, true><<<(1024 * 1024 + 255) / 256, 256, 0, stream>>>(
        part, fchg1_b, hx_mid_bf, 1024 * 1024, 1024, 4);
    gemm_bf16<true><<<dim3(4, 8, 8), 256, 0, stream>>>(
        hx_mid_bf, fchg2Wbf, nullptr, part, 1024, 512, 1024, 128);
    reduce_partial2<false, false><<<(1024 * 512 + 255) / 256, 256, 0, stream>>>(
        part, fchg2_b, hx_out, 1024 * 512, 512, 8);

    // ---------- fingerprint + text (bf16 padded paths) ----------
    gemm_bf16<true><<<dim3(1, 8, 8), 256, 0, stream>>>(
        fp_bf, fc1Wbf, nullptr, part, 1024, 128, 2560, 320);
    reduce_partial<true><<<(1024 * 128 + 255) / 256, 256, 0, stream>>>(
        part, fc1_b, h1, 1024 * 128, 128, 8);
    launch_gemm64(h1, fc2_W, fc2_b, fp_o, NB, HID, FP2, false, part, stream);
    gemm_bf16<true><<<dim3(4, 8, 4), 256, 0, stream>>>(
        text_bf, fc3Wbf, nullptr, part, 1024, 512, 768, 192);
    reduce_partial2<false, false><<<(1024 * 512 + 255) / 256, 256, 0, stream>>>(
        part, fc3_b, tt, 1024 * 512, 512, 4);

    // ---------- fusion attention (bf16 pipeline) ----------
    pack_tokens_bf<<<(4096 * 512 + 255) / 256, 256, 0, stream>>>(fp_o, xg_out, hx_out, tt, in_t_bf);
    cvt_qkv_w<<<(6144 * 512 + 255) / 256, 256, 0, stream>>>(Wq, Wk, Wv, Wqkv_bf);
    gemm_bf16<false><<<dim3(6144 / 128, 4096 / 128), 256, 0, stream>>>(
        in_t_bf, Wqkv_bf, qkv_bf, nullptr, 4096, 6144, 512, 512);
    attn_conv<<<NB, 256, 0, stream>>>(qkv_bf, conv_W, conv_b, cbuf_bf);
    cvt_w_pad<<<(1024 * 4096 + 255) / 256, 256, 0, stream>>>(mlp1_W, mlp1W_bf, 1024, 4080, 4096);
    gemm_bf16<true><<<dim3(8, 8, 8), 256, 0, stream>>>(
        cbuf_bf, mlp1W_bf, nullptr, part, 1024, 1024, 4096, 512);
    reduce_partial<true><<<(1024 * 1024 + 255) / 256, 256, 0, stream>>>(
        part, mlp1_b, m1, 1024 * 1024, 1024, 8);
    rowdot<<<256, 256, 0, stream>>>(m1, mlp2_W, mlp2_b, out_y, NB, 1024);
}